// Round 1
// baseline (1058.140 us; speedup 1.0000x reference)
//
#include <hip/hip_runtime.h>

#define NN 50000
#define EE 800000
#define HH 256
#define EPSBN 1e-5f

// ---------------- CSR build ----------------

__global__ void zero_deg(int* __restrict__ deg) {
    int i = blockIdx.x * blockDim.x + threadIdx.x;
    if (i < NN) deg[i] = 0;
}

__global__ void count_deg(const int* __restrict__ dst, int* __restrict__ deg) {
    int e = blockIdx.x * blockDim.x + threadIdx.x;
    if (e < EE) atomicAdd(&deg[dst[e]], 1);
}

// single-block exclusive scan over deg -> rowstart, cursor, invdeg
__global__ void scan_deg(const int* __restrict__ deg, int* __restrict__ rowstart,
                         int* __restrict__ cursor, float* __restrict__ invdeg) {
    __shared__ int sd[1024];
    __shared__ int s_base;
    if (threadIdx.x == 0) s_base = 0;
    __syncthreads();
    for (int start = 0; start < NN; start += 1024) {
        int i = start + (int)threadIdx.x;
        int v = (i < NN) ? deg[i] : 0;
        sd[threadIdx.x] = v;
        __syncthreads();
        #pragma unroll
        for (int off = 1; off < 1024; off <<= 1) {
            int t = (threadIdx.x >= (unsigned)off) ? sd[threadIdx.x - off] : 0;
            __syncthreads();
            sd[threadIdx.x] += t;
            __syncthreads();
        }
        int incl  = sd[threadIdx.x];
        int total = sd[1023];
        int base  = s_base;
        __syncthreads();
        if (threadIdx.x == 0) s_base = base + total;
        if (i < NN) {
            int rs = base + incl - v;   // exclusive
            rowstart[i] = rs;
            cursor[i]   = rs;
            invdeg[i]   = 1.0f / (float)(v > 1 ? v : 1);
        }
        __syncthreads();
    }
    if (threadIdx.x == 0) rowstart[NN] = s_base;
}

__global__ void fill_csr(const int* __restrict__ src, const int* __restrict__ dst,
                         int* __restrict__ cursor, int* __restrict__ col) {
    int e = blockIdx.x * blockDim.x + threadIdx.x;
    if (e < EE) {
        int d = dst[e];
        int pos = atomicAdd(&cursor[d], 1);
        col[pos] = src[e];
    }
}

// ---------------- mean aggregation: one wave per node ----------------

template<int C>
__global__ void agg_mean(const float* __restrict__ h, const int* __restrict__ rowstart,
                         const int* __restrict__ col, const float* __restrict__ invdeg,
                         float* __restrict__ agg) {
    int wid  = (int)((blockIdx.x * blockDim.x + threadIdx.x) >> 6);
    int lane = (int)(threadIdx.x & 63);
    if (wid >= NN) return;
    constexpr int C4 = C / 4;          // float4 slots per row (32 or 64)
    if (lane < C4) {
        int beg = rowstart[wid], end = rowstart[wid + 1];
        float inv = invdeg[wid];
        float4 acc = make_float4(0.f, 0.f, 0.f, 0.f);
        for (int j = beg; j < end; ++j) {
            int s = col[j];
            float4 v = *(const float4*)(h + (size_t)s * C + lane * 4);
            acc.x += v.x; acc.y += v.y; acc.z += v.z; acc.w += v.w;
        }
        acc.x *= inv; acc.y *= inv; acc.z *= inv; acc.w *= inv;
        *(float4*)(agg + (size_t)wid * C + lane * 4) = acc;
    }
}

// ---------------- fused dual-GEMM + bias + BN(eval) + ReLU ----------------
// out[i][j] = relu( (agg[i]@Wl + hin[i]@Wr + b - rm) * g*rsqrt(rv+eps) + bt )
// 64x64 tile, 256 threads, 4x4 micro-tile, K staged 16 at a time in LDS.

template<int C>
__global__ __launch_bounds__(256)
void gemm_bn_relu(const float* __restrict__ Aagg, const float* __restrict__ Ain,
                  const float* __restrict__ Wl,   const float* __restrict__ Wr,
                  const float* __restrict__ bias, const float* __restrict__ gamma,
                  const float* __restrict__ beta, const float* __restrict__ rmean,
                  const float* __restrict__ rvar, float* __restrict__ out) {
    __shared__ float As[16][68];   // [k][row], padded
    __shared__ float Bs[16][68];   // [k][col], padded (row start stays 16B-aligned)
    const int tid = (int)threadIdx.x;
    const int tx = tid & 15, ty = tid >> 4;
    const int row0 = (int)blockIdx.x * 64, col0 = (int)blockIdx.y * 64;
    float acc[4][4] = {};
    const int lr  = tid >> 2, lkq = tid & 3;    // A load: row lr (0..63), k-quad lkq
    const int lkk = tid >> 4, ljq = tid & 15;   // B load: k lkk (0..15), col-quad ljq

    for (int phase = 0; phase < 2; ++phase) {
        const float* __restrict__ A = phase ? Ain : Aagg;
        const float* __restrict__ B = phase ? Wr  : Wl;
        for (int k0 = 0; k0 < C; k0 += 16) {
            float4 av = make_float4(0.f, 0.f, 0.f, 0.f);
            int arow = row0 + lr;
            if (arow < NN) av = *(const float4*)(A + (size_t)arow * C + k0 + lkq * 4);
            float4 bv = *(const float4*)(B + (size_t)(k0 + lkk) * HH + col0 + ljq * 4);
            __syncthreads();               // WAR vs previous compute
            As[lkq * 4 + 0][lr] = av.x;
            As[lkq * 4 + 1][lr] = av.y;
            As[lkq * 4 + 2][lr] = av.z;
            As[lkq * 4 + 3][lr] = av.w;
            *(float4*)&Bs[lkk][ljq * 4] = bv;
            __syncthreads();
            #pragma unroll
            for (int kk = 0; kk < 16; ++kk) {
                float4 a4 = *(const float4*)&As[kk][ty * 4];
                float4 b4 = *(const float4*)&Bs[kk][tx * 4];
                float a_[4] = {a4.x, a4.y, a4.z, a4.w};
                float b_[4] = {b4.x, b4.y, b4.z, b4.w};
                #pragma unroll
                for (int i = 0; i < 4; ++i)
                    #pragma unroll
                    for (int j = 0; j < 4; ++j)
                        acc[i][j] += a_[i] * b_[j];
            }
        }
    }

    // epilogue: fold bias + BN + ReLU
    float sj[4], cj[4];
    #pragma unroll
    for (int j = 0; j < 4; ++j) {
        int jj = col0 + tx * 4 + j;
        float s = gamma[jj] * rsqrtf(rvar[jj] + EPSBN);
        sj[j] = s;
        cj[j] = (bias[jj] - rmean[jj]) * s + beta[jj];
    }
    #pragma unroll
    for (int i = 0; i < 4; ++i) {
        int row = row0 + ty * 4 + i;
        if (row < NN) {
            float4 v;
            float t0 = acc[i][0] * sj[0] + cj[0];
            float t1 = acc[i][1] * sj[1] + cj[1];
            float t2 = acc[i][2] * sj[2] + cj[2];
            float t3 = acc[i][3] * sj[3] + cj[3];
            v.x = t0 > 0.f ? t0 : 0.f;
            v.y = t1 > 0.f ? t1 : 0.f;
            v.z = t2 > 0.f ? t2 : 0.f;
            v.w = t3 > 0.f ? t3 : 0.f;
            *(float4*)(out + (size_t)row * HH + col0 + tx * 4) = v;
        }
    }
}

// ---------------- launch ----------------

static inline size_t alignup(size_t x) { return (x + 511) & ~(size_t)511; }

extern "C" void kernel_launch(void* const* d_in, const int* in_sizes, int n_in,
                              void* d_out, int out_size, void* d_ws, size_t ws_size,
                              hipStream_t stream) {
    const float* x   = (const float*)d_in[0];
    const int*   ei  = (const int*)d_in[1];
    const int*   src = ei;
    const int*   dst = ei + EE;
    const float* gamma = (const float*)d_in[2];
    const float* beta  = (const float*)d_in[3];
    const float* rmean = (const float*)d_in[4];
    const float* rvar  = (const float*)d_in[5];
    const float* Wl0 = (const float*)d_in[6];
    const float* Wr0 = (const float*)d_in[7];
    const float* b0  = (const float*)d_in[8];
    const float* Wl1 = (const float*)d_in[9];
    const float* Wr1 = (const float*)d_in[10];
    const float* b1  = (const float*)d_in[11];
    const float* Wl2 = (const float*)d_in[12];
    const float* Wr2 = (const float*)d_in[13];
    const float* b2  = (const float*)d_in[14];
    float* out = (float*)d_out;

    char* w = (char*)d_ws;
    size_t off = 0;
    int*   deg      = (int*)(w + off);  off += alignup(NN * 4);
    int*   cursor   = (int*)(w + off);  off += alignup(NN * 4);
    int*   rowstart = (int*)(w + off);  off += alignup((NN + 1) * 4);
    float* invdeg   = (float*)(w + off); off += alignup(NN * 4);
    int*   col      = (int*)(w + off);  off += alignup((size_t)EE * 4);
    float* agg      = (float*)(w + off); off += alignup((size_t)NN * HH * 4);
    float* buf0     = (float*)(w + off); off += alignup((size_t)NN * HH * 4);
    float* buf1     = (float*)(w + off); off += alignup((size_t)NN * HH * 4);
    (void)ws_size; (void)n_in; (void)in_sizes; (void)out_size;

    // CSR build
    zero_deg <<<(NN + 255) / 256, 256, 0, stream>>>(deg);
    count_deg<<<(EE + 255) / 256, 256, 0, stream>>>(dst, deg);
    scan_deg <<<1, 1024, 0, stream>>>(deg, rowstart, cursor, invdeg);
    fill_csr <<<(EE + 255) / 256, 256, 0, stream>>>(src, dst, cursor, col);

    const dim3 gemm_grid((NN + 63) / 64, HH / 64);
    const int agg_grid = (NN * 64 + 255) / 256;

    // layer 0 (C=128)
    agg_mean<128><<<agg_grid, 256, 0, stream>>>(x, rowstart, col, invdeg, agg);
    gemm_bn_relu<128><<<gemm_grid, 256, 0, stream>>>(agg, x, Wl0, Wr0, b0,
        gamma + 0 * HH, beta + 0 * HH, rmean + 0 * HH, rvar + 0 * HH, buf0);

    // layer 1 (C=256)
    agg_mean<256><<<agg_grid, 256, 0, stream>>>(buf0, rowstart, col, invdeg, agg);
    gemm_bn_relu<256><<<gemm_grid, 256, 0, stream>>>(agg, buf0, Wl1, Wr1, b1,
        gamma + 1 * HH, beta + 1 * HH, rmean + 1 * HH, rvar + 1 * HH, buf1);

    // layer 2 (C=256)
    agg_mean<256><<<agg_grid, 256, 0, stream>>>(buf1, rowstart, col, invdeg, agg);
    gemm_bn_relu<256><<<gemm_grid, 256, 0, stream>>>(agg, buf1, Wl2, Wr2, b2,
        gamma + 2 * HH, beta + 2 * HH, rmean + 2 * HH, rvar + 2 * HH, out);
}

// Round 2
// 671.957 us; speedup vs baseline: 1.5747x; 1.5747x over previous
//
#include <hip/hip_runtime.h>
#include <hip/hip_bf16.h>

#define NN 50000
#define PADN 50048            // 782*64 — padded row count for OOB-safe staging
#define EE 800000
#define HH 256
#define EPSBN 1e-5f

typedef unsigned int uint32;
typedef __attribute__((ext_vector_type(8))) short short8;   // 8 bf16 = 4 VGPR
typedef __attribute__((ext_vector_type(4))) float f32x4;

__device__ __forceinline__ float bf2f(unsigned short u) {
    union { uint32 u; float f; } c; c.u = ((uint32)u) << 16; return c.f;
}
__device__ __forceinline__ unsigned short f2bf(float f) {
    __hip_bfloat16 h = __float2bfloat16(f);   // RNE
    return *reinterpret_cast<unsigned short*>(&h);
}

// ---------------- CSR build ----------------

__global__ void zero_deg(int* __restrict__ deg) {
    int i = blockIdx.x * blockDim.x + threadIdx.x;
    if (i < NN) deg[i] = 0;
}

__global__ void count_deg(const int* __restrict__ dst, int* __restrict__ deg) {
    int e = blockIdx.x * blockDim.x + threadIdx.x;
    if (e < EE) atomicAdd(&deg[dst[e]], 1);
}

// one block, per-thread serial chunk + single 1024-wide scan
__global__ void scan_deg(const int* __restrict__ deg, int* __restrict__ rowstart,
                         int* __restrict__ cursor, float* __restrict__ invdeg) {
    __shared__ int part[1024];
    const int t = (int)threadIdx.x;
    const int per = (NN + 1023) / 1024;          // 49
    const int b = t * per;
    const int e = (b + per < NN) ? b + per : NN;
    int s = 0;
    for (int i = b; i < e; ++i) s += deg[i];
    part[t] = s;
    __syncthreads();
    #pragma unroll
    for (int off = 1; off < 1024; off <<= 1) {
        int v = (t >= off) ? part[t - off] : 0;
        __syncthreads();
        part[t] += v;
        __syncthreads();
    }
    int run = part[t] - s;                        // exclusive prefix
    for (int i = b; i < e; ++i) {
        int d = deg[i];
        rowstart[i] = run; cursor[i] = run;
        invdeg[i] = 1.0f / (float)(d > 1 ? d : 1);
        run += d;
    }
    if (t == 1023) rowstart[NN] = run;
}

__global__ void fill_csr(const int* __restrict__ src, const int* __restrict__ dst,
                         int* __restrict__ cursor, int* __restrict__ col) {
    int e = blockIdx.x * blockDim.x + threadIdx.x;
    if (e < EE) {
        int d = dst[e];
        int pos = atomicAdd(&cursor[d], 1);
        col[pos] = src[e];
    }
}

// ---------------- input conversion / weight packing ----------------

__global__ void cvt_x(const float* __restrict__ x, unsigned short* __restrict__ xb) {
    int i = blockIdx.x * blockDim.x + threadIdx.x;
    if (i < PADN * 128) {
        float f = (i < NN * 128) ? x[i] : 0.f;
        xb[i] = f2bf(f);
    }
}

// Wpack layout (bf16 elems): idx = ((s*16 + nf)*512 + l*8 + e)
//   s = mat*KS + ks (mat0=Wl, mat1=Wr), k = ks*32 + (l>>4)*8 + e, n = nf*16 + (l&15)
__global__ void pack_w(const float* __restrict__ Wl, const float* __restrict__ Wr,
                       unsigned short* __restrict__ Wpack, int C) {
    int idx = blockIdx.x * blockDim.x + threadIdx.x;
    if (idx >= 2 * C * 256) return;
    int e  = idx & 7;
    int l  = (idx >> 3) & 63;
    int nf = (idx >> 9) & 15;
    int s  = idx >> 13;
    int KS = C / 32;
    const float* W = (s < KS) ? Wl : Wr;
    int ks = (s < KS) ? s : s - KS;
    int k = ks * 32 + (l >> 4) * 8 + e;
    int n = nf * 16 + (l & 15);
    Wpack[idx] = f2bf(W[(size_t)k * HH + n]);
}

// ---------------- mean aggregation (bf16 in / bf16 out), one wave per node ----------------

template<int C>
__global__ void agg_mean_b(const unsigned short* __restrict__ h, const int* __restrict__ rowstart,
                           const int* __restrict__ col, const float* __restrict__ invdeg,
                           unsigned short* __restrict__ agg) {
    const int wid = (int)((blockIdx.x * blockDim.x + threadIdx.x) >> 6);
    const int l   = (int)(threadIdx.x & 63);
    if (wid >= NN) return;
    const int beg = rowstart[wid], end = rowstart[wid + 1];
    const float inv = invdeg[wid];
    if (C == 128) {
        float a0 = 0.f, a1 = 0.f;
        const unsigned short* base = h + l * 2;
        for (int j = beg; j < end; ++j) {
            uint32 v = *(const uint32*)(base + (size_t)col[j] * C);
            a0 += bf2f((unsigned short)(v & 0xffff));
            a1 += bf2f((unsigned short)(v >> 16));
        }
        uint32 o = (uint32)f2bf(a0 * inv) | ((uint32)f2bf(a1 * inv) << 16);
        *(uint32*)(agg + (size_t)wid * C + l * 2) = o;
    } else {
        float a0 = 0.f, a1 = 0.f, a2 = 0.f, a3 = 0.f;
        const unsigned short* base = h + l * 4;
        for (int j = beg; j < end; ++j) {
            uint2 v = *(const uint2*)(base + (size_t)col[j] * C);
            a0 += bf2f((unsigned short)(v.x & 0xffff));
            a1 += bf2f((unsigned short)(v.x >> 16));
            a2 += bf2f((unsigned short)(v.y & 0xffff));
            a3 += bf2f((unsigned short)(v.y >> 16));
        }
        uint2 o;
        o.x = (uint32)f2bf(a0 * inv) | ((uint32)f2bf(a1 * inv) << 16);
        o.y = (uint32)f2bf(a2 * inv) | ((uint32)f2bf(a3 * inv) << 16);
        *(uint2*)(agg + (size_t)wid * C + l * 4) = o;
    }
}

// ---------------- MFMA GEMM: out = relu(BN(agg@Wl + h@Wr + b)) ----------------
// 64 rows x 256 cols per block, 4 waves (one per 64-col slab), K = 2*C fused.
// A staged fragment-major via global_load_lds (lane's 16B == its MFMA fragment),
// B fragments loaded direct global->VGPR from packed weights.

template<int C, bool FINAL>
__global__ __launch_bounds__(256)
void gemm_mfma(const unsigned short* __restrict__ Aagg, const unsigned short* __restrict__ Ain,
               const unsigned short* __restrict__ Wpack,
               const float* __restrict__ bias, const float* __restrict__ gamma,
               const float* __restrict__ beta, const float* __restrict__ rmean,
               const float* __restrict__ rvar,
               float* __restrict__ outf, unsigned short* __restrict__ outb)
{
    constexpr int KS = C / 32;      // k-steps per matrix
    constexpr int S  = 2 * KS;      // fused K loop (agg@Wl then h@Wr)
    __shared__ unsigned short Alds[2][4][512];   // dbuf x 4 m-frags x (64 lanes * 8 bf16)
    const int tid = (int)threadIdx.x;
    const int wid = tid >> 6;       // wave -> 64-col slab
    const int l   = tid & 63;
    const int row0 = (int)blockIdx.x * 64;

    // staging address: wave wid stages m-frag wid
    const int srow  = row0 + wid * 16 + (l & 15);
    const int skoff = (l >> 4) * 8;

    f32x4 acc[4][4];
    #pragma unroll
    for (int m = 0; m < 4; ++m)
        #pragma unroll
        for (int n = 0; n < 4; ++n)
            acc[m][n] = (f32x4){0.f, 0.f, 0.f, 0.f};

    auto stage = [&](int buf, int s) {
        const unsigned short* Asrc = (s < KS) ? Aagg : Ain;
        const int ks = (s < KS) ? s : s - KS;
        const unsigned short* gp = Asrc + (size_t)srow * C + ks * 32 + skoff;
        __builtin_amdgcn_global_load_lds(
            (const __attribute__((address_space(1))) uint32*)gp,
            (__attribute__((address_space(3))) uint32*)(&Alds[buf][wid][0]),
            16, 0, 0);
    };

    stage(0, 0);
    int cur = 0;
    for (int s = 0; s < S; ++s) {
        __syncthreads();                       // Alds[cur] staged (vmcnt drained)
        if (s + 1 < S) stage(cur ^ 1, s + 1);  // prefetch next k-step
        short8 b[4];
        #pragma unroll
        for (int n = 0; n < 4; ++n) {
            size_t off = ((size_t)s * 16 + wid * 4 + n) * 512 + l * 8;
            b[n] = *(const short8*)(Wpack + off);
        }
        short8 a[4];
        #pragma unroll
        for (int m = 0; m < 4; ++m)
            a[m] = *(const short8*)(&Alds[cur][m][l * 8]);   // ds_read_b128, conflict-free
        #pragma unroll
        for (int m = 0; m < 4; ++m)
            #pragma unroll
            for (int n = 0; n < 4; ++n)
                acc[m][n] = __builtin_amdgcn_mfma_f32_16x16x32_bf16(a[m], b[n], acc[m][n], 0, 0, 0);
        cur ^= 1;
    }

    // epilogue: fold bias + BN + ReLU; C/D layout: col=lane&15, row=(lane>>4)*4+reg
    #pragma unroll
    for (int n = 0; n < 4; ++n) {
        const int jj = wid * 64 + n * 16 + (l & 15);
        const float sc = gamma[jj] * rsqrtf(rvar[jj] + EPSBN);
        const float c0 = (bias[jj] - rmean[jj]) * sc + beta[jj];
        #pragma unroll
        for (int m = 0; m < 4; ++m) {
            const int rb = row0 + m * 16 + (l >> 4) * 4;
            #pragma unroll
            for (int j = 0; j < 4; ++j) {
                const int r = rb + j;
                if (r < NN) {
                    float v = acc[m][n][j] * sc + c0;
                    v = v > 0.f ? v : 0.f;
                    if (FINAL) outf[(size_t)r * HH + jj] = v;
                    else       outb[(size_t)r * HH + jj] = f2bf(v);
                }
            }
        }
    }
}

// ---------------- launch ----------------

static inline size_t alignup(size_t x) { return (x + 511) & ~(size_t)511; }

extern "C" void kernel_launch(void* const* d_in, const int* in_sizes, int n_in,
                              void* d_out, int out_size, void* d_ws, size_t ws_size,
                              hipStream_t stream) {
    const float* x   = (const float*)d_in[0];
    const int*   ei  = (const int*)d_in[1];
    const int*   src = ei;
    const int*   dst = ei + EE;
    const float* gamma = (const float*)d_in[2];
    const float* beta  = (const float*)d_in[3];
    const float* rmean = (const float*)d_in[4];
    const float* rvar  = (const float*)d_in[5];
    const float* Wl0 = (const float*)d_in[6];
    const float* Wr0 = (const float*)d_in[7];
    const float* b0  = (const float*)d_in[8];
    const float* Wl1 = (const float*)d_in[9];
    const float* Wr1 = (const float*)d_in[10];
    const float* b1  = (const float*)d_in[11];
    const float* Wl2 = (const float*)d_in[12];
    const float* Wr2 = (const float*)d_in[13];
    const float* b2  = (const float*)d_in[14];
    float* out = (float*)d_out;
    (void)ws_size; (void)n_in; (void)in_sizes; (void)out_size;

    char* w = (char*)d_ws;
    size_t off = 0;
    int*   deg      = (int*)(w + off);   off += alignup(NN * 4);
    int*   cursor   = (int*)(w + off);   off += alignup(NN * 4);
    int*   rowstart = (int*)(w + off);   off += alignup((NN + 1) * 4);
    float* invdeg   = (float*)(w + off); off += alignup(NN * 4);
    int*   col      = (int*)(w + off);   off += alignup((size_t)EE * 4);
    unsigned short* xb   = (unsigned short*)(w + off); off += alignup((size_t)PADN * 128 * 2);
    unsigned short* agg  = (unsigned short*)(w + off); off += alignup((size_t)PADN * HH * 2);
    unsigned short* h1   = (unsigned short*)(w + off); off += alignup((size_t)PADN * HH * 2);
    unsigned short* h2   = (unsigned short*)(w + off); off += alignup((size_t)PADN * HH * 2);
    unsigned short* Wp0  = (unsigned short*)(w + off); off += alignup((size_t)2 * 128 * 256 * 2);
    unsigned short* Wp1  = (unsigned short*)(w + off); off += alignup((size_t)2 * 256 * 256 * 2);
    unsigned short* Wp2  = (unsigned short*)(w + off); off += alignup((size_t)2 * 256 * 256 * 2);

    // CSR build
    zero_deg <<<(NN + 255) / 256, 256, 0, stream>>>(deg);
    count_deg<<<(EE + 255) / 256, 256, 0, stream>>>(dst, deg);
    scan_deg <<<1, 1024, 0, stream>>>(deg, rowstart, cursor, invdeg);
    fill_csr <<<(EE + 255) / 256, 256, 0, stream>>>(src, dst, cursor, col);

    // conversions / packing
    cvt_x <<<(PADN * 128 + 255) / 256, 256, 0, stream>>>(x, xb);
    pack_w<<<(2 * 128 * 256 + 255) / 256, 256, 0, stream>>>(Wl0, Wr0, Wp0, 128);
    pack_w<<<(2 * 256 * 256 + 255) / 256, 256, 0, stream>>>(Wl1, Wr1, Wp1, 256);
    pack_w<<<(2 * 256 * 256 + 255) / 256, 256, 0, stream>>>(Wl2, Wr2, Wp2, 256);

    const int agg_grid  = (NN * 64 + 255) / 256;
    const int gemm_grid = PADN / 64;   // 782

    // layer 0 (C=128)
    agg_mean_b<128><<<agg_grid, 256, 0, stream>>>(xb, rowstart, col, invdeg, agg);
    gemm_mfma<128, false><<<gemm_grid, 256, 0, stream>>>(agg, xb, Wp0,
        b0, gamma + 0 * HH, beta + 0 * HH, rmean + 0 * HH, rvar + 0 * HH, nullptr, h1);

    // layer 1 (C=256)
    agg_mean_b<256><<<agg_grid, 256, 0, stream>>>(h1, rowstart, col, invdeg, agg);
    gemm_mfma<256, false><<<gemm_grid, 256, 0, stream>>>(agg, h1, Wp1,
        b1, gamma + 1 * HH, beta + 1 * HH, rmean + 1 * HH, rvar + 1 * HH, nullptr, h2);

    // layer 2 (C=256)
    agg_mean_b<256><<<agg_grid, 256, 0, stream>>>(h2, rowstart, col, invdeg, agg);
    gemm_mfma<256, true><<<gemm_grid, 256, 0, stream>>>(agg, h2, Wp2,
        b2, gamma + 2 * HH, beta + 2 * HH, rmean + 2 * HH, rvar + 2 * HH, out, nullptr);
}

// Round 3
// 449.006 us; speedup vs baseline: 2.3566x; 1.4965x over previous
//
#include <hip/hip_runtime.h>
#include <hip/hip_bf16.h>

#define NN 50000
#define PADN 50048            // 782*64 — padded row count for OOB-safe staging
#define EE 800000
#define HH 256
#define EPSBN 1e-5f
#define NBLK ((NN + 255) / 256)   // 196 scan blocks

typedef unsigned int uint32;
typedef __attribute__((ext_vector_type(8))) short short8;   // 8 bf16 = 4 VGPR
typedef __attribute__((ext_vector_type(4))) float f32x4;

__device__ __forceinline__ float bf2f(unsigned short u) {
    union { uint32 u; float f; } c; c.u = ((uint32)u) << 16; return c.f;
}
__device__ __forceinline__ unsigned short f2bf(float f) {
    __hip_bfloat16 h = __float2bfloat16(f);   // RNE
    return *reinterpret_cast<unsigned short*>(&h);
}

// ---------------- CSR build ----------------

__global__ void zero_deg(int* __restrict__ deg) {
    int i = blockIdx.x * blockDim.x + threadIdx.x;
    if (i < NN) deg[i] = 0;
}

__global__ void count_deg(const int* __restrict__ dst, int* __restrict__ deg) {
    int e = blockIdx.x * blockDim.x + threadIdx.x;
    if (e < EE) atomicAdd(&deg[dst[e]], 1);
}

// pass 1: per-block sum of deg
__global__ void scan_part(const int* __restrict__ deg, int* __restrict__ bsum) {
    __shared__ int sd[256];
    const int t = (int)threadIdx.x;
    const int i = (int)blockIdx.x * 256 + t;
    sd[t] = (i < NN) ? deg[i] : 0;
    __syncthreads();
    #pragma unroll
    for (int off = 128; off > 0; off >>= 1) {
        if (t < off) sd[t] += sd[t + off];
        __syncthreads();
    }
    if (t == 0) bsum[blockIdx.x] = sd[0];
}

// pass 2: single block scans the 196 block sums -> exclusive offsets; writes total
__global__ void scan_top(const int* __restrict__ bsum, int* __restrict__ boff,
                         int* __restrict__ rowstart) {
    __shared__ int sd[256];
    const int t = (int)threadIdx.x;
    int v = (t < NBLK) ? bsum[t] : 0;
    sd[t] = v;
    __syncthreads();
    #pragma unroll
    for (int off = 1; off < 256; off <<= 1) {
        int u = (t >= off) ? sd[t - off] : 0;
        __syncthreads();
        sd[t] += u;
        __syncthreads();
    }
    if (t < NBLK) boff[t] = sd[t] - v;          // exclusive
    if (t == NBLK - 1) rowstart[NN] = sd[t];    // total == EE
}

// pass 3: per-block exclusive scan + block offset -> rowstart/cursor/invdeg
__global__ void scan_fin(const int* __restrict__ deg, const int* __restrict__ boff,
                         int* __restrict__ rowstart, int* __restrict__ cursor,
                         float* __restrict__ invdeg) {
    __shared__ int sd[256];
    const int t = (int)threadIdx.x;
    const int i = (int)blockIdx.x * 256 + t;
    const int v = (i < NN) ? deg[i] : 0;
    sd[t] = v;
    __syncthreads();
    #pragma unroll
    for (int off = 1; off < 256; off <<= 1) {
        int u = (t >= off) ? sd[t - off] : 0;
        __syncthreads();
        sd[t] += u;
        __syncthreads();
    }
    if (i < NN) {
        int rs = boff[blockIdx.x] + sd[t] - v;
        rowstart[i] = rs;
        cursor[i]   = rs;
        invdeg[i]   = 1.0f / (float)(v > 1 ? v : 1);
    }
}

__global__ void fill_csr(const int* __restrict__ src, const int* __restrict__ dst,
                         int* __restrict__ cursor, int* __restrict__ col) {
    int e = blockIdx.x * blockDim.x + threadIdx.x;
    if (e < EE) {
        int d = dst[e];
        int pos = atomicAdd(&cursor[d], 1);
        col[pos] = src[e];
    }
}

// ---------------- input conversion / weight packing ----------------

__global__ void cvt_x(const float* __restrict__ x, unsigned short* __restrict__ xb) {
    int i = blockIdx.x * blockDim.x + threadIdx.x;
    if (i < PADN * 128) {
        float f = (i < NN * 128) ? x[i] : 0.f;
        xb[i] = f2bf(f);
    }
}

// Wpack layout (bf16 elems): idx = ((s*16 + nf)*512 + l*8 + e)
//   s = mat*KS + ks (mat0=Wl, mat1=Wr), k = ks*32 + (l>>4)*8 + e, n = nf*16 + (l&15)
__global__ void pack_w(const float* __restrict__ Wl, const float* __restrict__ Wr,
                       unsigned short* __restrict__ Wpack, int C) {
    int idx = blockIdx.x * blockDim.x + threadIdx.x;
    if (idx >= 2 * C * 256) return;
    int e  = idx & 7;
    int l  = (idx >> 3) & 63;
    int nf = (idx >> 9) & 15;
    int s  = idx >> 13;
    int KS = C / 32;
    const float* W = (s < KS) ? Wl : Wr;
    int ks = (s < KS) ? s : s - KS;
    int k = ks * 32 + (l >> 4) * 8 + e;
    int n = nf * 16 + (l & 15);
    Wpack[idx] = f2bf(W[(size_t)k * HH + n]);
}

// ---------------- mean aggregation (bf16), one wave per node ----------------
// Multi-neighbor per wave-iteration: 16B/lane loads, cross-subwave shfl reduce.

template<int C>
__global__ void agg_mean_b(const unsigned short* __restrict__ h, const int* __restrict__ rowstart,
                           const int* __restrict__ col, const float* __restrict__ invdeg,
                           unsigned short* __restrict__ agg) {
    const int wid = (int)((blockIdx.x * blockDim.x + threadIdx.x) >> 6);
    const int l   = (int)(threadIdx.x & 63);
    if (wid >= NN) return;
    const int beg = rowstart[wid], end = rowstart[wid + 1];
    const float inv = invdeg[wid];
    float a[8] = {0.f, 0.f, 0.f, 0.f, 0.f, 0.f, 0.f, 0.f};

    if (C == 256) {
        const int half = l >> 5;            // 2 neighbors per iteration
        const int cl   = l & 31;            // 32 lanes x 8 bf16 = 256 ch
        const unsigned short* base = h + cl * 8;
        for (int j = beg + half; j < end; j += 2) {
            uint4 v = *(const uint4*)(base + (size_t)col[j] * C);
            a[0] += bf2f((unsigned short)(v.x & 0xffff)); a[1] += bf2f((unsigned short)(v.x >> 16));
            a[2] += bf2f((unsigned short)(v.y & 0xffff)); a[3] += bf2f((unsigned short)(v.y >> 16));
            a[4] += bf2f((unsigned short)(v.z & 0xffff)); a[5] += bf2f((unsigned short)(v.z >> 16));
            a[6] += bf2f((unsigned short)(v.w & 0xffff)); a[7] += bf2f((unsigned short)(v.w >> 16));
        }
        #pragma unroll
        for (int k = 0; k < 8; ++k) a[k] += __shfl_xor(a[k], 32, 64);
        if (half == 0) {
            uint4 o;
            o.x = (uint32)f2bf(a[0] * inv) | ((uint32)f2bf(a[1] * inv) << 16);
            o.y = (uint32)f2bf(a[2] * inv) | ((uint32)f2bf(a[3] * inv) << 16);
            o.z = (uint32)f2bf(a[4] * inv) | ((uint32)f2bf(a[5] * inv) << 16);
            o.w = (uint32)f2bf(a[6] * inv) | ((uint32)f2bf(a[7] * inv) << 16);
            *(uint4*)(agg + (size_t)wid * C + cl * 8) = o;
        }
    } else {  // C == 128
        const int q  = l >> 4;              // 4 neighbors per iteration
        const int cl = l & 15;              // 16 lanes x 8 bf16 = 128 ch
        const unsigned short* base = h + cl * 8;
        for (int j = beg + q; j < end; j += 4) {
            uint4 v = *(const uint4*)(base + (size_t)col[j] * C);
            a[0] += bf2f((unsigned short)(v.x & 0xffff)); a[1] += bf2f((unsigned short)(v.x >> 16));
            a[2] += bf2f((unsigned short)(v.y & 0xffff)); a[3] += bf2f((unsigned short)(v.y >> 16));
            a[4] += bf2f((unsigned short)(v.z & 0xffff)); a[5] += bf2f((unsigned short)(v.z >> 16));
            a[6] += bf2f((unsigned short)(v.w & 0xffff)); a[7] += bf2f((unsigned short)(v.w >> 16));
        }
        #pragma unroll
        for (int k = 0; k < 8; ++k) {
            a[k] += __shfl_xor(a[k], 16, 64);
            a[k] += __shfl_xor(a[k], 32, 64);
        }
        if (q == 0) {
            uint4 o;
            o.x = (uint32)f2bf(a[0] * inv) | ((uint32)f2bf(a[1] * inv) << 16);
            o.y = (uint32)f2bf(a[2] * inv) | ((uint32)f2bf(a[3] * inv) << 16);
            o.z = (uint32)f2bf(a[4] * inv) | ((uint32)f2bf(a[5] * inv) << 16);
            o.w = (uint32)f2bf(a[6] * inv) | ((uint32)f2bf(a[7] * inv) << 16);
            *(uint4*)(agg + (size_t)wid * C + cl * 8) = o;
        }
    }
}

// ---------------- MFMA GEMM: out = relu(BN(agg@Wl + h@Wr + b)) ----------------
// 64 rows x 256 cols per block, 4 waves (one per 64-col slab), K = 2*C fused.

template<int C, bool FINAL>
__global__ __launch_bounds__(256)
void gemm_mfma(const unsigned short* __restrict__ Aagg, const unsigned short* __restrict__ Ain,
               const unsigned short* __restrict__ Wpack,
               const float* __restrict__ bias, const float* __restrict__ gamma,
               const float* __restrict__ beta, const float* __restrict__ rmean,
               const float* __restrict__ rvar,
               float* __restrict__ outf, unsigned short* __restrict__ outb)
{
    constexpr int KS = C / 32;      // k-steps per matrix
    constexpr int S  = 2 * KS;      // fused K loop (agg@Wl then h@Wr)
    __shared__ unsigned short Alds[2][4][512];   // dbuf x 4 m-frags x (64 lanes * 8 bf16)
    const int tid = (int)threadIdx.x;
    const int wid = tid >> 6;       // wave -> 64-col slab
    const int l   = tid & 63;
    const int row0 = (int)blockIdx.x * 64;

    // staging address: wave wid stages m-frag wid
    const int srow  = row0 + wid * 16 + (l & 15);
    const int skoff = (l >> 4) * 8;

    f32x4 acc[4][4];
    #pragma unroll
    for (int m = 0; m < 4; ++m)
        #pragma unroll
        for (int n = 0; n < 4; ++n)
            acc[m][n] = (f32x4){0.f, 0.f, 0.f, 0.f};

    auto stage = [&](int buf, int s) {
        const unsigned short* Asrc = (s < KS) ? Aagg : Ain;
        const int ks = (s < KS) ? s : s - KS;
        const unsigned short* gp = Asrc + (size_t)srow * C + ks * 32 + skoff;
        __builtin_amdgcn_global_load_lds(
            (const __attribute__((address_space(1))) uint32*)gp,
            (__attribute__((address_space(3))) uint32*)(&Alds[buf][wid][0]),
            16, 0, 0);
    };

    stage(0, 0);
    int cur = 0;
    for (int s = 0; s < S; ++s) {
        __syncthreads();                       // Alds[cur] staged (vmcnt drained)
        if (s + 1 < S) stage(cur ^ 1, s + 1);  // prefetch next k-step
        short8 b[4];
        #pragma unroll
        for (int n = 0; n < 4; ++n) {
            size_t off = ((size_t)s * 16 + wid * 4 + n) * 512 + l * 8;
            b[n] = *(const short8*)(Wpack + off);
        }
        short8 a[4];
        #pragma unroll
        for (int m = 0; m < 4; ++m)
            a[m] = *(const short8*)(&Alds[cur][m][l * 8]);   // ds_read_b128, conflict-free
        #pragma unroll
        for (int m = 0; m < 4; ++m)
            #pragma unroll
            for (int n = 0; n < 4; ++n)
                acc[m][n] = __builtin_amdgcn_mfma_f32_16x16x32_bf16(a[m], b[n], acc[m][n], 0, 0, 0);
        cur ^= 1;
    }

    // epilogue: fold bias + BN + ReLU; C/D layout: col=lane&15, row=(lane>>4)*4+reg
    #pragma unroll
    for (int n = 0; n < 4; ++n) {
        const int jj = wid * 64 + n * 16 + (l & 15);
        const float sc = gamma[jj] * rsqrtf(rvar[jj] + EPSBN);
        const float c0 = (bias[jj] - rmean[jj]) * sc + beta[jj];
        #pragma unroll
        for (int m = 0; m < 4; ++m) {
            const int rb = row0 + m * 16 + (l >> 4) * 4;
            #pragma unroll
            for (int j = 0; j < 4; ++j) {
                const int r = rb + j;
                if (r < NN) {
                    float v = acc[m][n][j] * sc + c0;
                    v = v > 0.f ? v : 0.f;
                    if (FINAL) outf[(size_t)r * HH + jj] = v;
                    else       outb[(size_t)r * HH + jj] = f2bf(v);
                }
            }
        }
    }
}

// ---------------- launch ----------------

static inline size_t alignup(size_t x) { return (x + 511) & ~(size_t)511; }

extern "C" void kernel_launch(void* const* d_in, const int* in_sizes, int n_in,
                              void* d_out, int out_size, void* d_ws, size_t ws_size,
                              hipStream_t stream) {
    const float* x   = (const float*)d_in[0];
    const int*   ei  = (const int*)d_in[1];
    const int*   src = ei;
    const int*   dst = ei + EE;
    const float* gamma = (const float*)d_in[2];
    const float* beta  = (const float*)d_in[3];
    const float* rmean = (const float*)d_in[4];
    const float* rvar  = (const float*)d_in[5];
    const float* Wl0 = (const float*)d_in[6];
    const float* Wr0 = (const float*)d_in[7];
    const float* b0  = (const float*)d_in[8];
    const float* Wl1 = (const float*)d_in[9];
    const float* Wr1 = (const float*)d_in[10];
    const float* b1  = (const float*)d_in[11];
    const float* Wl2 = (const float*)d_in[12];
    const float* Wr2 = (const float*)d_in[13];
    const float* b2  = (const float*)d_in[14];
    float* out = (float*)d_out;
    (void)ws_size; (void)n_in; (void)in_sizes; (void)out_size;

    char* w = (char*)d_ws;
    size_t off = 0;
    int*   deg      = (int*)(w + off);   off += alignup(NN * 4);
    int*   cursor   = (int*)(w + off);   off += alignup(NN * 4);
    int*   rowstart = (int*)(w + off);   off += alignup((NN + 1) * 4);
    float* invdeg   = (float*)(w + off); off += alignup(NN * 4);
    int*   bsum     = (int*)(w + off);   off += alignup(NBLK * 4);
    int*   boff     = (int*)(w + off);   off += alignup(NBLK * 4);
    int*   col      = (int*)(w + off);   off += alignup((size_t)EE * 4);
    unsigned short* xb   = (unsigned short*)(w + off); off += alignup((size_t)PADN * 128 * 2);
    unsigned short* agg  = (unsigned short*)(w + off); off += alignup((size_t)PADN * HH * 2);
    unsigned short* h1   = (unsigned short*)(w + off); off += alignup((size_t)PADN * HH * 2);
    unsigned short* h2   = (unsigned short*)(w + off); off += alignup((size_t)PADN * HH * 2);
    unsigned short* Wp0  = (unsigned short*)(w + off); off += alignup((size_t)2 * 128 * 256 * 2);
    unsigned short* Wp1  = (unsigned short*)(w + off); off += alignup((size_t)2 * 256 * 256 * 2);
    unsigned short* Wp2  = (unsigned short*)(w + off); off += alignup((size_t)2 * 256 * 256 * 2);

    // CSR build (hierarchical scan: 3 small grid-wide passes)
    zero_deg <<<(NN + 255) / 256, 256, 0, stream>>>(deg);
    count_deg<<<(EE + 255) / 256, 256, 0, stream>>>(dst, deg);
    scan_part<<<NBLK, 256, 0, stream>>>(deg, bsum);
    scan_top <<<1, 256, 0, stream>>>(bsum, boff, rowstart);
    scan_fin <<<NBLK, 256, 0, stream>>>(deg, boff, rowstart, cursor, invdeg);
    fill_csr <<<(EE + 255) / 256, 256, 0, stream>>>(src, dst, cursor, col);

    // conversions / packing
    cvt_x <<<(PADN * 128 + 255) / 256, 256, 0, stream>>>(x, xb);
    pack_w<<<(2 * 128 * 256 + 255) / 256, 256, 0, stream>>>(Wl0, Wr0, Wp0, 128);
    pack_w<<<(2 * 256 * 256 + 255) / 256, 256, 0, stream>>>(Wl1, Wr1, Wp1, 256);
    pack_w<<<(2 * 256 * 256 + 255) / 256, 256, 0, stream>>>(Wl2, Wr2, Wp2, 256);

    const int agg_grid  = (NN * 64 + 255) / 256;
    const int gemm_grid = PADN / 64;   // 782

    // layer 0 (C=128)
    agg_mean_b<128><<<agg_grid, 256, 0, stream>>>(xb, rowstart, col, invdeg, agg);
    gemm_mfma<128, false><<<gemm_grid, 256, 0, stream>>>(agg, xb, Wp0,
        b0, gamma + 0 * HH, beta + 0 * HH, rmean + 0 * HH, rvar + 0 * HH, nullptr, h1);

    // layer 1 (C=256)
    agg_mean_b<256><<<agg_grid, 256, 0, stream>>>(h1, rowstart, col, invdeg, agg);
    gemm_mfma<256, false><<<gemm_grid, 256, 0, stream>>>(agg, h1, Wp1,
        b1, gamma + 1 * HH, beta + 1 * HH, rmean + 1 * HH, rvar + 1 * HH, nullptr, h2);

    // layer 2 (C=256)
    agg_mean_b<256><<<agg_grid, 256, 0, stream>>>(h2, rowstart, col, invdeg, agg);
    gemm_mfma<256, true><<<gemm_grid, 256, 0, stream>>>(agg, h2, Wp2,
        b2, gamma + 2 * HH, beta + 2 * HH, rmean + 2 * HH, rvar + 2 * HH, out, nullptr);
}

// Round 4
// 396.868 us; speedup vs baseline: 2.6662x; 1.1314x over previous
//
#include <hip/hip_runtime.h>
#include <hip/hip_bf16.h>

#define NN 50000
#define PADN 50048            // 782*64 — padded row count for OOB-safe staging
#define EE 800000
#define HH 256
#define EPSBN 1e-5f
#define NBLK ((NN + 255) / 256)   // 196 scan blocks

typedef unsigned int uint32;
typedef __attribute__((ext_vector_type(8))) short short8;   // 8 bf16 = 4 VGPR
typedef __attribute__((ext_vector_type(4))) float f32x4;

__device__ __forceinline__ float bf2f(unsigned short u) {
    union { uint32 u; float f; } c; c.u = ((uint32)u) << 16; return c.f;
}
__device__ __forceinline__ unsigned short f2bf(float f) {
    __hip_bfloat16 h = __float2bfloat16(f);   // RNE
    return *reinterpret_cast<unsigned short*>(&h);
}

// ---------------- CSR build ----------------

// count in-degree AND record each edge's rank within its destination row
__global__ void count_rank(const int* __restrict__ dst, int* __restrict__ deg,
                           int* __restrict__ rank) {
    int e = blockIdx.x * blockDim.x + threadIdx.x;
    if (e < EE) rank[e] = atomicAdd(&deg[dst[e]], 1);
}

// pass 1: per-block sum of deg
__global__ void scan_part(const int* __restrict__ deg, int* __restrict__ bsum) {
    __shared__ int sd[256];
    const int t = (int)threadIdx.x;
    const int i = (int)blockIdx.x * 256 + t;
    sd[t] = (i < NN) ? deg[i] : 0;
    __syncthreads();
    #pragma unroll
    for (int off = 128; off > 0; off >>= 1) {
        if (t < off) sd[t] += sd[t + off];
        __syncthreads();
    }
    if (t == 0) bsum[blockIdx.x] = sd[0];
}

// pass 2: single block scans the 196 block sums -> exclusive offsets
__global__ void scan_top(const int* __restrict__ bsum, int* __restrict__ boff,
                         int* __restrict__ rowstart) {
    __shared__ int sd[256];
    const int t = (int)threadIdx.x;
    int v = (t < NBLK) ? bsum[t] : 0;
    sd[t] = v;
    __syncthreads();
    #pragma unroll
    for (int off = 1; off < 256; off <<= 1) {
        int u = (t >= off) ? sd[t - off] : 0;
        __syncthreads();
        sd[t] += u;
        __syncthreads();
    }
    if (t < NBLK) boff[t] = sd[t] - v;          // exclusive
    if (t == NBLK - 1) rowstart[NN] = sd[t];    // total == EE
}

// pass 3: per-block exclusive scan + block offset -> rowstart
__global__ void scan_fin(const int* __restrict__ deg, const int* __restrict__ boff,
                         int* __restrict__ rowstart) {
    __shared__ int sd[256];
    const int t = (int)threadIdx.x;
    const int i = (int)blockIdx.x * 256 + t;
    const int v = (i < NN) ? deg[i] : 0;
    sd[t] = v;
    __syncthreads();
    #pragma unroll
    for (int off = 1; off < 256; off <<= 1) {
        int u = (t >= off) ? sd[t - off] : 0;
        __syncthreads();
        sd[t] += u;
        __syncthreads();
    }
    if (i < NN) rowstart[i] = boff[blockIdx.x] + sd[t] - v;
}

// atomic-free CSR fill using precomputed ranks
__global__ void fill_csr2(const int* __restrict__ src, const int* __restrict__ dst,
                          const int* __restrict__ rank, const int* __restrict__ rowstart,
                          int* __restrict__ col) {
    int e = blockIdx.x * blockDim.x + threadIdx.x;
    if (e < EE) col[rowstart[dst[e]] + rank[e]] = src[e];
}

// ---------------- input conversion / weight packing ----------------

__global__ void cvt_x(const float* __restrict__ x, unsigned short* __restrict__ xb) {
    int i = blockIdx.x * blockDim.x + threadIdx.x;
    if (i < PADN * 128) {
        float f = (i < NN * 128) ? x[i] : 0.f;
        xb[i] = f2bf(f);
    }
}

// Wpack layout (bf16 elems): idx = ((s*16 + nf)*512 + l*8 + e)
//   s = mat*KS + ks (mat0=Wl, mat1=Wr), k = ks*32 + (l>>4)*8 + e, n = nf*16 + (l&15)
__global__ void pack_w(const float* __restrict__ Wl, const float* __restrict__ Wr,
                       unsigned short* __restrict__ Wpack, int C) {
    int idx = blockIdx.x * blockDim.x + threadIdx.x;
    if (idx >= 2 * C * 256) return;
    int e  = idx & 7;
    int l  = (idx >> 3) & 63;
    int nf = (idx >> 9) & 15;
    int s  = idx >> 13;
    int KS = C / 32;
    const float* W = (s < KS) ? Wl : Wr;
    int ks = (s < KS) ? s : s - KS;
    int k = ks * 32 + (l >> 4) * 8 + e;
    int n = nf * 16 + (l & 15);
    Wpack[idx] = f2bf(W[(size_t)k * HH + n]);
}

// ---------------- mean aggregation (bf16), one wave per node ----------------
// 2 independent 16B gathers per lane per iteration (4 or 8 neighbors/iter).

__device__ __forceinline__ void acc8(float* a, uint4 v) {
    a[0] += bf2f((unsigned short)(v.x & 0xffff)); a[1] += bf2f((unsigned short)(v.x >> 16));
    a[2] += bf2f((unsigned short)(v.y & 0xffff)); a[3] += bf2f((unsigned short)(v.y >> 16));
    a[4] += bf2f((unsigned short)(v.z & 0xffff)); a[5] += bf2f((unsigned short)(v.z >> 16));
    a[6] += bf2f((unsigned short)(v.w & 0xffff)); a[7] += bf2f((unsigned short)(v.w >> 16));
}

template<int C>
__global__ void agg_mean_b(const unsigned short* __restrict__ h, const int* __restrict__ rowstart,
                           const int* __restrict__ col,
                           unsigned short* __restrict__ agg) {
    const int wid = (int)((blockIdx.x * blockDim.x + threadIdx.x) >> 6);
    const int l   = (int)(threadIdx.x & 63);
    if (wid >= NN) return;
    const int beg = rowstart[wid], end = rowstart[wid + 1];
    const int d   = end - beg;
    const float inv = 1.0f / (float)(d > 1 ? d : 1);
    float a[8] = {0.f, 0.f, 0.f, 0.f, 0.f, 0.f, 0.f, 0.f};

    if (C == 256) {
        const int half = l >> 5;            // 2 sub-waves; each handles 2 nbrs/iter
        const int cl   = l & 31;            // 32 lanes x 8 bf16 = 256 ch
        const unsigned short* base = h + cl * 8;
        int j = beg + half;
        for (; j + 2 < end; j += 4) {       // nbrs j and j+2 (independent loads)
            int c0 = col[j], c1 = col[j + 2];
            uint4 v0 = *(const uint4*)(base + (size_t)c0 * C);
            uint4 v1 = *(const uint4*)(base + (size_t)c1 * C);
            acc8(a, v0); acc8(a, v1);
        }
        if (j < end) {
            uint4 v0 = *(const uint4*)(base + (size_t)col[j] * C);
            acc8(a, v0);
        }
        #pragma unroll
        for (int k = 0; k < 8; ++k) a[k] += __shfl_xor(a[k], 32, 64);
        if (half == 0) {
            uint4 o;
            o.x = (uint32)f2bf(a[0] * inv) | ((uint32)f2bf(a[1] * inv) << 16);
            o.y = (uint32)f2bf(a[2] * inv) | ((uint32)f2bf(a[3] * inv) << 16);
            o.z = (uint32)f2bf(a[4] * inv) | ((uint32)f2bf(a[5] * inv) << 16);
            o.w = (uint32)f2bf(a[6] * inv) | ((uint32)f2bf(a[7] * inv) << 16);
            *(uint4*)(agg + (size_t)wid * C + cl * 8) = o;
        }
    } else {  // C == 128
        const int q  = l >> 4;              // 4 sub-waves; each handles 2 nbrs/iter
        const int cl = l & 15;              // 16 lanes x 8 bf16 = 128 ch
        const unsigned short* base = h + cl * 8;
        int j = beg + q;
        for (; j + 4 < end; j += 8) {       // nbrs j and j+4
            int c0 = col[j], c1 = col[j + 4];
            uint4 v0 = *(const uint4*)(base + (size_t)c0 * C);
            uint4 v1 = *(const uint4*)(base + (size_t)c1 * C);
            acc8(a, v0); acc8(a, v1);
        }
        if (j < end) {
            uint4 v0 = *(const uint4*)(base + (size_t)col[j] * C);
            acc8(a, v0);
        }
        #pragma unroll
        for (int k = 0; k < 8; ++k) {
            a[k] += __shfl_xor(a[k], 16, 64);
            a[k] += __shfl_xor(a[k], 32, 64);
        }
        if (q == 0) {
            uint4 o;
            o.x = (uint32)f2bf(a[0] * inv) | ((uint32)f2bf(a[1] * inv) << 16);
            o.y = (uint32)f2bf(a[2] * inv) | ((uint32)f2bf(a[3] * inv) << 16);
            o.z = (uint32)f2bf(a[4] * inv) | ((uint32)f2bf(a[5] * inv) << 16);
            o.w = (uint32)f2bf(a[6] * inv) | ((uint32)f2bf(a[7] * inv) << 16);
            *(uint4*)(agg + (size_t)wid * C + cl * 8) = o;
        }
    }
}

// ---------------- MFMA GEMM: out = relu(BN(agg@Wl + h@Wr + b)) ----------------
// 64 rows x 256 cols per block, 4 waves (one per 64-col slab), K = 2*C fused.
// bf16 layers: C-tile repacked through LDS for coalesced uint4 stores.

#define CPAD 260   // bf16 elems per Clds row (row stride 520 B; banks shift 2/row)

template<int C, bool FINAL>
__global__ __launch_bounds__(256)
void gemm_mfma(const unsigned short* __restrict__ Aagg, const unsigned short* __restrict__ Ain,
               const unsigned short* __restrict__ Wpack,
               const float* __restrict__ bias, const float* __restrict__ gamma,
               const float* __restrict__ beta, const float* __restrict__ rmean,
               const float* __restrict__ rvar,
               float* __restrict__ outf, unsigned short* __restrict__ outb)
{
    constexpr int KS = C / 32;      // k-steps per matrix
    constexpr int S  = 2 * KS;      // fused K loop (agg@Wl then h@Wr)
    __shared__ unsigned short Alds[2][4][512];   // dbuf x 4 m-frags x (64 lanes * 8 bf16)
    __shared__ unsigned short Clds[64 * CPAD];   // bf16 C-tile repack (non-FINAL)
    const int tid = (int)threadIdx.x;
    const int wid = tid >> 6;       // wave -> 64-col slab
    const int l   = tid & 63;
    const int row0 = (int)blockIdx.x * 64;

    // staging address: wave wid stages m-frag wid
    const int srow  = row0 + wid * 16 + (l & 15);
    const int skoff = (l >> 4) * 8;

    f32x4 acc[4][4];
    #pragma unroll
    for (int m = 0; m < 4; ++m)
        #pragma unroll
        for (int n = 0; n < 4; ++n)
            acc[m][n] = (f32x4){0.f, 0.f, 0.f, 0.f};

    auto stage = [&](int buf, int s) {
        const unsigned short* Asrc = (s < KS) ? Aagg : Ain;
        const int ks = (s < KS) ? s : s - KS;
        const unsigned short* gp = Asrc + (size_t)srow * C + ks * 32 + skoff;
        __builtin_amdgcn_global_load_lds(
            (const __attribute__((address_space(1))) uint32*)gp,
            (__attribute__((address_space(3))) uint32*)(&Alds[buf][wid][0]),
            16, 0, 0);
    };

    stage(0, 0);
    int cur = 0;
    for (int s = 0; s < S; ++s) {
        __syncthreads();                       // Alds[cur] staged (vmcnt drained)
        if (s + 1 < S) stage(cur ^ 1, s + 1);  // prefetch next k-step
        short8 b[4];
        #pragma unroll
        for (int n = 0; n < 4; ++n) {
            size_t off = ((size_t)s * 16 + wid * 4 + n) * 512 + l * 8;
            b[n] = *(const short8*)(Wpack + off);
        }
        short8 a[4];
        #pragma unroll
        for (int m = 0; m < 4; ++m)
            a[m] = *(const short8*)(&Alds[cur][m][l * 8]);   // ds_read_b128, conflict-free
        #pragma unroll
        for (int m = 0; m < 4; ++m)
            #pragma unroll
            for (int n = 0; n < 4; ++n)
                acc[m][n] = __builtin_amdgcn_mfma_f32_16x16x32_bf16(a[m], b[n], acc[m][n], 0, 0, 0);
        cur ^= 1;
    }

    // epilogue: fold bias + BN + ReLU; C/D layout: col=lane&15, row=(lane>>4)*4+reg
    #pragma unroll
    for (int n = 0; n < 4; ++n) {
        const int jj = wid * 64 + n * 16 + (l & 15);
        const float sc = gamma[jj] * rsqrtf(rvar[jj] + EPSBN);
        const float c0 = (bias[jj] - rmean[jj]) * sc + beta[jj];
        #pragma unroll
        for (int m = 0; m < 4; ++m) {
            const int rb = m * 16 + (l >> 4) * 4;
            #pragma unroll
            for (int j = 0; j < 4; ++j) {
                float v = acc[m][n][j] * sc + c0;
                v = v > 0.f ? v : 0.f;
                if (FINAL) {
                    const int r = row0 + rb + j;
                    if (r < NN) outf[(size_t)r * HH + jj] = v;
                } else {
                    Clds[(rb + j) * CPAD + jj] = f2bf(v);
                }
            }
        }
    }
    if (!FINAL) {
        __syncthreads();
        // linear write-out: 8 x fully-coalesced 16B stores per thread
        #pragma unroll
        for (int i = 0; i < 8; ++i) {
            const int row  = i * 8 + (tid >> 5);
            const int col8 = (tid & 31) * 8;
            uint4 v = *(const uint4*)&Clds[row * CPAD + col8];
            *(uint4*)(outb + ((size_t)(row0 + row)) * HH + col8) = v;
        }
    }
}

// ---------------- launch ----------------

static inline size_t alignup(size_t x) { return (x + 511) & ~(size_t)511; }

extern "C" void kernel_launch(void* const* d_in, const int* in_sizes, int n_in,
                              void* d_out, int out_size, void* d_ws, size_t ws_size,
                              hipStream_t stream) {
    const float* x   = (const float*)d_in[0];
    const int*   ei  = (const int*)d_in[1];
    const int*   src = ei;
    const int*   dst = ei + EE;
    const float* gamma = (const float*)d_in[2];
    const float* beta  = (const float*)d_in[3];
    const float* rmean = (const float*)d_in[4];
    const float* rvar  = (const float*)d_in[5];
    const float* Wl0 = (const float*)d_in[6];
    const float* Wr0 = (const float*)d_in[7];
    const float* b0  = (const float*)d_in[8];
    const float* Wl1 = (const float*)d_in[9];
    const float* Wr1 = (const float*)d_in[10];
    const float* b1  = (const float*)d_in[11];
    const float* Wl2 = (const float*)d_in[12];
    const float* Wr2 = (const float*)d_in[13];
    const float* b2  = (const float*)d_in[14];
    float* out = (float*)d_out;
    (void)ws_size; (void)n_in; (void)in_sizes; (void)out_size;

    char* w = (char*)d_ws;
    size_t off = 0;
    int*   deg      = (int*)(w + off);   off += alignup(NN * 4);
    int*   rank     = (int*)(w + off);   off += alignup((size_t)EE * 4);
    int*   rowstart = (int*)(w + off);   off += alignup((NN + 1) * 4);
    int*   bsum     = (int*)(w + off);   off += alignup(NBLK * 4);
    int*   boff     = (int*)(w + off);   off += alignup(NBLK * 4);
    int*   col      = (int*)(w + off);   off += alignup((size_t)EE * 4);
    unsigned short* xb   = (unsigned short*)(w + off); off += alignup((size_t)PADN * 128 * 2);
    unsigned short* agg  = (unsigned short*)(w + off); off += alignup((size_t)PADN * HH * 2);
    unsigned short* h1   = (unsigned short*)(w + off); off += alignup((size_t)PADN * HH * 2);
    unsigned short* h2   = (unsigned short*)(w + off); off += alignup((size_t)PADN * HH * 2);
    unsigned short* Wp0  = (unsigned short*)(w + off); off += alignup((size_t)2 * 128 * 256 * 2);
    unsigned short* Wp1  = (unsigned short*)(w + off); off += alignup((size_t)2 * 256 * 256 * 2);
    unsigned short* Wp2  = (unsigned short*)(w + off); off += alignup((size_t)2 * 256 * 256 * 2);

    // CSR build (rank trick: fill pass is atomic-free)
    hipMemsetAsync(deg, 0, NN * 4, stream);
    count_rank<<<(EE + 255) / 256, 256, 0, stream>>>(dst, deg, rank);
    scan_part<<<NBLK, 256, 0, stream>>>(deg, bsum);
    scan_top <<<1, 256, 0, stream>>>(bsum, boff, rowstart);
    scan_fin <<<NBLK, 256, 0, stream>>>(deg, boff, rowstart);
    fill_csr2<<<(EE + 255) / 256, 256, 0, stream>>>(src, dst, rank, rowstart, col);

    // conversions / packing
    cvt_x <<<(PADN * 128 + 255) / 256, 256, 0, stream>>>(x, xb);
    pack_w<<<(2 * 128 * 256 + 255) / 256, 256, 0, stream>>>(Wl0, Wr0, Wp0, 128);
    pack_w<<<(2 * 256 * 256 + 255) / 256, 256, 0, stream>>>(Wl1, Wr1, Wp1, 256);
    pack_w<<<(2 * 256 * 256 + 255) / 256, 256, 0, stream>>>(Wl2, Wr2, Wp2, 256);

    const int agg_grid  = (NN * 64 + 255) / 256;
    const int gemm_grid = PADN / 64;   // 782

    // layer 0 (C=128)
    agg_mean_b<128><<<agg_grid, 256, 0, stream>>>(xb, rowstart, col, agg);
    gemm_mfma<128, false><<<gemm_grid, 256, 0, stream>>>(agg, xb, Wp0,
        b0, gamma + 0 * HH, beta + 0 * HH, rmean + 0 * HH, rvar + 0 * HH, nullptr, h1);

    // layer 1 (C=256)
    agg_mean_b<256><<<agg_grid, 256, 0, stream>>>(h1, rowstart, col, agg);
    gemm_mfma<256, false><<<gemm_grid, 256, 0, stream>>>(agg, h1, Wp1,
        b1, gamma + 1 * HH, beta + 1 * HH, rmean + 1 * HH, rvar + 1 * HH, nullptr, h2);

    // layer 2 (C=256)
    agg_mean_b<256><<<agg_grid, 256, 0, stream>>>(h2, rowstart, col, agg);
    gemm_mfma<256, true><<<gemm_grid, 256, 0, stream>>>(agg, h2, Wp2,
        b2, gamma + 2 * HH, beta + 2 * HH, rmean + 2 * HH, rvar + 2 * HH, out, nullptr);
}

// Round 5
// 394.992 us; speedup vs baseline: 2.6789x; 1.0047x over previous
//
#include <hip/hip_runtime.h>
#include <hip/hip_bf16.h>

#define NN 50000
#define PADN 50048            // 782*64 — padded row count for OOB-safe staging
#define EE 800000
#define HH 256
#define EPSBN 1e-5f
#define NBLK ((NN + 255) / 256)   // 196 scan blocks

typedef unsigned int uint32;
typedef __attribute__((ext_vector_type(8))) short short8;   // 8 bf16 = 4 VGPR
typedef __attribute__((ext_vector_type(4))) float f32x4;

__device__ __forceinline__ float bf2f(unsigned short u) {
    union { uint32 u; float f; } c; c.u = ((uint32)u) << 16; return c.f;
}
__device__ __forceinline__ unsigned short f2bf(float f) {
    __hip_bfloat16 h = __float2bfloat16(f);   // RNE
    return *reinterpret_cast<unsigned short*>(&h);
}

// ---------------- CSR build ----------------

// count in-degree AND record each edge's rank within its destination row
__global__ void count_rank(const int* __restrict__ dst, int* __restrict__ deg,
                           int* __restrict__ rank) {
    int e = blockIdx.x * blockDim.x + threadIdx.x;
    if (e < EE) rank[e] = atomicAdd(&deg[dst[e]], 1);
}

// pass 1: per-block sum of deg
__global__ void scan_part(const int* __restrict__ deg, int* __restrict__ bsum) {
    __shared__ int sd[256];
    const int t = (int)threadIdx.x;
    const int i = (int)blockIdx.x * 256 + t;
    sd[t] = (i < NN) ? deg[i] : 0;
    __syncthreads();
    #pragma unroll
    for (int off = 128; off > 0; off >>= 1) {
        if (t < off) sd[t] += sd[t + off];
        __syncthreads();
    }
    if (t == 0) bsum[blockIdx.x] = sd[0];
}

// pass 2: single block scans the 196 block sums -> exclusive offsets
__global__ void scan_top(const int* __restrict__ bsum, int* __restrict__ boff,
                         int* __restrict__ rowstart) {
    __shared__ int sd[256];
    const int t = (int)threadIdx.x;
    int v = (t < NBLK) ? bsum[t] : 0;
    sd[t] = v;
    __syncthreads();
    #pragma unroll
    for (int off = 1; off < 256; off <<= 1) {
        int u = (t >= off) ? sd[t - off] : 0;
        __syncthreads();
        sd[t] += u;
        __syncthreads();
    }
    if (t < NBLK) boff[t] = sd[t] - v;          // exclusive
    if (t == NBLK - 1) rowstart[NN] = sd[t];    // total == EE
}

// pass 3: per-block exclusive scan + block offset -> rowstart
__global__ void scan_fin(const int* __restrict__ deg, const int* __restrict__ boff,
                         int* __restrict__ rowstart) {
    __shared__ int sd[256];
    const int t = (int)threadIdx.x;
    const int i = (int)blockIdx.x * 256 + t;
    const int v = (i < NN) ? deg[i] : 0;
    sd[t] = v;
    __syncthreads();
    #pragma unroll
    for (int off = 1; off < 256; off <<= 1) {
        int u = (t >= off) ? sd[t - off] : 0;
        __syncthreads();
        sd[t] += u;
        __syncthreads();
    }
    if (i < NN) rowstart[i] = boff[blockIdx.x] + sd[t] - v;
}

// atomic-free CSR fill using precomputed ranks
__global__ void fill_csr2(const int* __restrict__ src, const int* __restrict__ dst,
                          const int* __restrict__ rank, const int* __restrict__ rowstart,
                          int* __restrict__ col) {
    int e = blockIdx.x * blockDim.x + threadIdx.x;
    if (e < EE) col[rowstart[dst[e]] + rank[e]] = src[e];
}

// ---------------- input conversion / weight packing ----------------

__global__ void cvt_x(const float* __restrict__ x, unsigned short* __restrict__ xb) {
    int i = blockIdx.x * blockDim.x + threadIdx.x;
    if (i < PADN * 128) {
        float f = (i < NN * 128) ? x[i] : 0.f;
        xb[i] = f2bf(f);
    }
}

// Wpack layout (bf16 elems): idx = ((s*16 + nf)*512 + l*8 + e)
//   s = mat*KS + ks (mat0=Wl, mat1=Wr), k = ks*32 + (l>>4)*8 + e, n = nf*16 + (l&15)
__global__ void pack_w(const float* __restrict__ Wl, const float* __restrict__ Wr,
                       unsigned short* __restrict__ Wpack, int C) {
    int idx = blockIdx.x * blockDim.x + threadIdx.x;
    if (idx >= 2 * C * 256) return;
    int e  = idx & 7;
    int l  = (idx >> 3) & 63;
    int nf = (idx >> 9) & 15;
    int s  = idx >> 13;
    int KS = C / 32;
    const float* W = (s < KS) ? Wl : Wr;
    int ks = (s < KS) ? s : s - KS;
    int k = ks * 32 + (l >> 4) * 8 + e;
    int n = nf * 16 + (l & 15);
    Wpack[idx] = f2bf(W[(size_t)k * HH + n]);
}

// ---------------- mean aggregation (bf16), one wave per node ----------------
// 4 independent 16B gathers per lane per iteration to hide L2/L3 latency.

__device__ __forceinline__ void acc8(float* a, uint4 v) {
    a[0] += bf2f((unsigned short)(v.x & 0xffff)); a[1] += bf2f((unsigned short)(v.x >> 16));
    a[2] += bf2f((unsigned short)(v.y & 0xffff)); a[3] += bf2f((unsigned short)(v.y >> 16));
    a[4] += bf2f((unsigned short)(v.z & 0xffff)); a[5] += bf2f((unsigned short)(v.z >> 16));
    a[6] += bf2f((unsigned short)(v.w & 0xffff)); a[7] += bf2f((unsigned short)(v.w >> 16));
}

template<int C>
__global__ void agg_mean_b(const unsigned short* __restrict__ h, const int* __restrict__ rowstart,
                           const int* __restrict__ col,
                           unsigned short* __restrict__ agg) {
    const int wid = (int)((blockIdx.x * blockDim.x + threadIdx.x) >> 6);
    const int l   = (int)(threadIdx.x & 63);
    if (wid >= NN) return;
    const int beg = rowstart[wid], end = rowstart[wid + 1];
    const int d   = end - beg;
    const float inv = 1.0f / (float)(d > 1 ? d : 1);
    float a[8] = {0.f, 0.f, 0.f, 0.f, 0.f, 0.f, 0.f, 0.f};

    if (C == 256) {
        const int half = l >> 5;            // 2 sub-waves x 32 lanes x 16B = row
        const int cl   = l & 31;
        const unsigned short* base = h + cl * 8;
        int j = beg + half;
        // 4-deep: neighbors j, j+2, j+4, j+6 (all independent loads)
        for (; j + 6 < end; j += 8) {
            int c0 = col[j], c1 = col[j + 2], c2 = col[j + 4], c3 = col[j + 6];
            uint4 v0 = *(const uint4*)(base + (size_t)c0 * C);
            uint4 v1 = *(const uint4*)(base + (size_t)c1 * C);
            uint4 v2 = *(const uint4*)(base + (size_t)c2 * C);
            uint4 v3 = *(const uint4*)(base + (size_t)c3 * C);
            acc8(a, v0); acc8(a, v1); acc8(a, v2); acc8(a, v3);
        }
        for (; j < end; j += 2) {
            uint4 v0 = *(const uint4*)(base + (size_t)col[j] * C);
            acc8(a, v0);
        }
        #pragma unroll
        for (int k = 0; k < 8; ++k) a[k] += __shfl_xor(a[k], 32, 64);
        if (half == 0) {
            uint4 o;
            o.x = (uint32)f2bf(a[0] * inv) | ((uint32)f2bf(a[1] * inv) << 16);
            o.y = (uint32)f2bf(a[2] * inv) | ((uint32)f2bf(a[3] * inv) << 16);
            o.z = (uint32)f2bf(a[4] * inv) | ((uint32)f2bf(a[5] * inv) << 16);
            o.w = (uint32)f2bf(a[6] * inv) | ((uint32)f2bf(a[7] * inv) << 16);
            *(uint4*)(agg + (size_t)wid * C + cl * 8) = o;
        }
    } else {  // C == 128
        const int q  = l >> 4;              // 4 sub-waves x 16 lanes x 16B = row
        const int cl = l & 15;
        const unsigned short* base = h + cl * 8;
        int j = beg + q;
        // 4-deep: neighbors j, j+4, j+8, j+12
        for (; j + 12 < end; j += 16) {
            int c0 = col[j], c1 = col[j + 4], c2 = col[j + 8], c3 = col[j + 12];
            uint4 v0 = *(const uint4*)(base + (size_t)c0 * C);
            uint4 v1 = *(const uint4*)(base + (size_t)c1 * C);
            uint4 v2 = *(const uint4*)(base + (size_t)c2 * C);
            uint4 v3 = *(const uint4*)(base + (size_t)c3 * C);
            acc8(a, v0); acc8(a, v1); acc8(a, v2); acc8(a, v3);
        }
        for (; j < end; j += 4) {
            uint4 v0 = *(const uint4*)(base + (size_t)col[j] * C);
            acc8(a, v0);
        }
        #pragma unroll
        for (int k = 0; k < 8; ++k) {
            a[k] += __shfl_xor(a[k], 16, 64);
            a[k] += __shfl_xor(a[k], 32, 64);
        }
        if (q == 0) {
            uint4 o;
            o.x = (uint32)f2bf(a[0] * inv) | ((uint32)f2bf(a[1] * inv) << 16);
            o.y = (uint32)f2bf(a[2] * inv) | ((uint32)f2bf(a[3] * inv) << 16);
            o.z = (uint32)f2bf(a[4] * inv) | ((uint32)f2bf(a[5] * inv) << 16);
            o.w = (uint32)f2bf(a[6] * inv) | ((uint32)f2bf(a[7] * inv) << 16);
            *(uint4*)(agg + (size_t)wid * C + cl * 8) = o;
        }
    }
}

// ---------------- MFMA GEMM: out = relu(BN(agg@Wl + h@Wr + b)) ----------------
// 64 rows x 256 cols per block, 4 waves (one per 64-col slab), K = 2*C fused.
// bf16 layers: C-tile repacked through LDS for coalesced uint4 stores.

#define CPAD 260   // bf16 elems per Clds row (row stride 520 B; banks shift 2/row)

template<int C, bool FINAL>
__global__ __launch_bounds__(256)
void gemm_mfma(const unsigned short* __restrict__ Aagg, const unsigned short* __restrict__ Ain,
               const unsigned short* __restrict__ Wpack,
               const float* __restrict__ bias, const float* __restrict__ gamma,
               const float* __restrict__ beta, const float* __restrict__ rmean,
               const float* __restrict__ rvar,
               float* __restrict__ outf, unsigned short* __restrict__ outb)
{
    constexpr int KS = C / 32;      // k-steps per matrix
    constexpr int S  = 2 * KS;      // fused K loop (agg@Wl then h@Wr)
    __shared__ unsigned short Alds[2][4][512];   // dbuf x 4 m-frags x (64 lanes * 8 bf16)
    __shared__ unsigned short Clds[64 * CPAD];   // bf16 C-tile repack (non-FINAL)
    const int tid = (int)threadIdx.x;
    const int wid = tid >> 6;       // wave -> 64-col slab
    const int l   = tid & 63;
    const int row0 = (int)blockIdx.x * 64;

    // staging address: wave wid stages m-frag wid
    const int srow  = row0 + wid * 16 + (l & 15);
    const int skoff = (l >> 4) * 8;

    f32x4 acc[4][4];
    #pragma unroll
    for (int m = 0; m < 4; ++m)
        #pragma unroll
        for (int n = 0; n < 4; ++n)
            acc[m][n] = (f32x4){0.f, 0.f, 0.f, 0.f};

    auto stage = [&](int buf, int s) {
        const unsigned short* Asrc = (s < KS) ? Aagg : Ain;
        const int ks = (s < KS) ? s : s - KS;
        const unsigned short* gp = Asrc + (size_t)srow * C + ks * 32 + skoff;
        __builtin_amdgcn_global_load_lds(
            (const __attribute__((address_space(1))) uint32*)gp,
            (__attribute__((address_space(3))) uint32*)(&Alds[buf][wid][0]),
            16, 0, 0);
    };

    stage(0, 0);
    int cur = 0;
    for (int s = 0; s < S; ++s) {
        __syncthreads();                       // Alds[cur] staged (vmcnt drained)
        if (s + 1 < S) stage(cur ^ 1, s + 1);  // prefetch next k-step
        short8 b[4];
        #pragma unroll
        for (int n = 0; n < 4; ++n) {
            size_t off = ((size_t)s * 16 + wid * 4 + n) * 512 + l * 8;
            b[n] = *(const short8*)(Wpack + off);
        }
        short8 a[4];
        #pragma unroll
        for (int m = 0; m < 4; ++m)
            a[m] = *(const short8*)(&Alds[cur][m][l * 8]);   // ds_read_b128, conflict-free
        #pragma unroll
        for (int m = 0; m < 4; ++m)
            #pragma unroll
            for (int n = 0; n < 4; ++n)
                acc[m][n] = __builtin_amdgcn_mfma_f32_16x16x32_bf16(a[m], b[n], acc[m][n], 0, 0, 0);
        cur ^= 1;
    }

    // epilogue: fold bias + BN + ReLU; C/D layout: col=lane&15, row=(lane>>4)*4+reg
    #pragma unroll
    for (int n = 0; n < 4; ++n) {
        const int jj = wid * 64 + n * 16 + (l & 15);
        const float sc = gamma[jj] * rsqrtf(rvar[jj] + EPSBN);
        const float c0 = (bias[jj] - rmean[jj]) * sc + beta[jj];
        #pragma unroll
        for (int m = 0; m < 4; ++m) {
            const int rb = m * 16 + (l >> 4) * 4;
            #pragma unroll
            for (int j = 0; j < 4; ++j) {
                float v = acc[m][n][j] * sc + c0;
                v = v > 0.f ? v : 0.f;
                if (FINAL) {
                    const int r = row0 + rb + j;
                    if (r < NN) outf[(size_t)r * HH + jj] = v;
                } else {
                    Clds[(rb + j) * CPAD + jj] = f2bf(v);
                }
            }
        }
    }
    if (!FINAL) {
        __syncthreads();
        // linear write-out: 8 x fully-coalesced 16B stores per thread
        #pragma unroll
        for (int i = 0; i < 8; ++i) {
            const int row  = i * 8 + (tid >> 5);
            const int col8 = (tid & 31) * 8;
            uint4 v = *(const uint4*)&Clds[row * CPAD + col8];
            *(uint4*)(outb + ((size_t)(row0 + row)) * HH + col8) = v;
        }
    }
}

// ---------------- launch ----------------

static inline size_t alignup(size_t x) { return (x + 511) & ~(size_t)511; }

extern "C" void kernel_launch(void* const* d_in, const int* in_sizes, int n_in,
                              void* d_out, int out_size, void* d_ws, size_t ws_size,
                              hipStream_t stream) {
    const float* x   = (const float*)d_in[0];
    const int*   ei  = (const int*)d_in[1];
    const int*   src = ei;
    const int*   dst = ei + EE;
    const float* gamma = (const float*)d_in[2];
    const float* beta  = (const float*)d_in[3];
    const float* rmean = (const float*)d_in[4];
    const float* rvar  = (const float*)d_in[5];
    const float* Wl0 = (const float*)d_in[6];
    const float* Wr0 = (const float*)d_in[7];
    const float* b0  = (const float*)d_in[8];
    const float* Wl1 = (const float*)d_in[9];
    const float* Wr1 = (const float*)d_in[10];
    const float* b1  = (const float*)d_in[11];
    const float* Wl2 = (const float*)d_in[12];
    const float* Wr2 = (const float*)d_in[13];
    const float* b2  = (const float*)d_in[14];
    float* out = (float*)d_out;
    (void)ws_size; (void)n_in; (void)in_sizes; (void)out_size;

    char* w = (char*)d_ws;
    size_t off = 0;
    int*   deg      = (int*)(w + off);   off += alignup(NN * 4);
    int*   rank     = (int*)(w + off);   off += alignup((size_t)EE * 4);
    int*   rowstart = (int*)(w + off);   off += alignup((NN + 1) * 4);
    int*   bsum     = (int*)(w + off);   off += alignup(NBLK * 4);
    int*   boff     = (int*)(w + off);   off += alignup(NBLK * 4);
    int*   col      = (int*)(w + off);   off += alignup((size_t)EE * 4);
    unsigned short* xb   = (unsigned short*)(w + off); off += alignup((size_t)PADN * 128 * 2);
    unsigned short* agg  = (unsigned short*)(w + off); off += alignup((size_t)PADN * HH * 2);
    unsigned short* h1   = (unsigned short*)(w + off); off += alignup((size_t)PADN * HH * 2);
    unsigned short* h2   = (unsigned short*)(w + off); off += alignup((size_t)PADN * HH * 2);
    unsigned short* Wp0  = (unsigned short*)(w + off); off += alignup((size_t)2 * 128 * 256 * 2);
    unsigned short* Wp1  = (unsigned short*)(w + off); off += alignup((size_t)2 * 256 * 256 * 2);
    unsigned short* Wp2  = (unsigned short*)(w + off); off += alignup((size_t)2 * 256 * 256 * 2);

    // CSR build (rank trick: fill pass is atomic-free)
    hipMemsetAsync(deg, 0, NN * 4, stream);
    count_rank<<<(EE + 255) / 256, 256, 0, stream>>>(dst, deg, rank);
    scan_part<<<NBLK, 256, 0, stream>>>(deg, bsum);
    scan_top <<<1, 256, 0, stream>>>(bsum, boff, rowstart);
    scan_fin <<<NBLK, 256, 0, stream>>>(deg, boff, rowstart);
    fill_csr2<<<(EE + 255) / 256, 256, 0, stream>>>(src, dst, rank, rowstart, col);

    // conversions / packing
    cvt_x <<<(PADN * 128 + 255) / 256, 256, 0, stream>>>(x, xb);
    pack_w<<<(2 * 128 * 256 + 255) / 256, 256, 0, stream>>>(Wl0, Wr0, Wp0, 128);
    pack_w<<<(2 * 256 * 256 + 255) / 256, 256, 0, stream>>>(Wl1, Wr1, Wp1, 256);
    pack_w<<<(2 * 256 * 256 + 255) / 256, 256, 0, stream>>>(Wl2, Wr2, Wp2, 256);

    const int agg_grid  = (NN * 64 + 255) / 256;
    const int gemm_grid = PADN / 64;   // 782

    // layer 0 (C=128)
    agg_mean_b<128><<<agg_grid, 256, 0, stream>>>(xb, rowstart, col, agg);
    gemm_mfma<128, false><<<gemm_grid, 256, 0, stream>>>(agg, xb, Wp0,
        b0, gamma + 0 * HH, beta + 0 * HH, rmean + 0 * HH, rvar + 0 * HH, nullptr, h1);

    // layer 1 (C=256)
    agg_mean_b<256><<<agg_grid, 256, 0, stream>>>(h1, rowstart, col, agg);
    gemm_mfma<256, false><<<gemm_grid, 256, 0, stream>>>(agg, h1, Wp1,
        b1, gamma + 1 * HH, beta + 1 * HH, rmean + 1 * HH, rvar + 1 * HH, nullptr, h2);

    // layer 2 (C=256)
    agg_mean_b<256><<<agg_grid, 256, 0, stream>>>(h2, rowstart, col, agg);
    gemm_mfma<256, true><<<gemm_grid, 256, 0, stream>>>(agg, h2, Wp2,
        b2, gamma + 2 * HH, beta + 2 * HH, rmean + 2 * HH, rvar + 2 * HH, out, nullptr);
}

// Round 6
// 350.632 us; speedup vs baseline: 3.0178x; 1.1265x over previous
//
#include <hip/hip_runtime.h>
#include <hip/hip_bf16.h>

#define NN 50000
#define PADN 50048            // 782*64 — padded row count for OOB-safe staging
#define EE 800000
#define HH 256
#define EPSBN 1e-5f
#define NBLK ((NN + 255) / 256)   // 196 scan blocks

typedef unsigned int uint32;
typedef __attribute__((ext_vector_type(8))) short short8;   // 8 bf16 = 4 VGPR
typedef __attribute__((ext_vector_type(4))) float f32x4;
typedef __attribute__((ext_vector_type(2))) float f32x2;

__device__ __forceinline__ float bf2f(unsigned short u) {
    union { uint32 u; float f; } c; c.u = ((uint32)u) << 16; return c.f;
}
__device__ __forceinline__ unsigned short f2bf(float f) {
    __hip_bfloat16 h = __float2bfloat16(f);   // RNE
    return *reinterpret_cast<unsigned short*>(&h);
}
// pack 4 floats -> 4 fp8 e4m3 (OCP on gfx950), RNE+sat
__device__ __forceinline__ uint32 pkfp8(float a, float b, float c, float d) {
    int r = 0;
    r = __builtin_amdgcn_cvt_pk_fp8_f32(a, b, r, false);   // bytes 0,1
    r = __builtin_amdgcn_cvt_pk_fp8_f32(c, d, r, true);    // bytes 2,3
    return (uint32)r;
}

// ---------------- CSR build ----------------

// count in-degree AND record each edge's rank within its destination row
__global__ void count_rank(const int* __restrict__ dst, int* __restrict__ deg,
                           int* __restrict__ rank) {
    int e = blockIdx.x * blockDim.x + threadIdx.x;
    if (e < EE) rank[e] = atomicAdd(&deg[dst[e]], 1);
}

// pass 1: per-block sum of deg
__global__ void scan_part(const int* __restrict__ deg, int* __restrict__ bsum) {
    __shared__ int sd[256];
    const int t = (int)threadIdx.x;
    const int i = (int)blockIdx.x * 256 + t;
    sd[t] = (i < NN) ? deg[i] : 0;
    __syncthreads();
    #pragma unroll
    for (int off = 128; off > 0; off >>= 1) {
        if (t < off) sd[t] += sd[t + off];
        __syncthreads();
    }
    if (t == 0) bsum[blockIdx.x] = sd[0];
}

// pass 2: single block scans the 196 block sums -> exclusive offsets
__global__ void scan_top(const int* __restrict__ bsum, int* __restrict__ boff,
                         int* __restrict__ rowstart) {
    __shared__ int sd[256];
    const int t = (int)threadIdx.x;
    int v = (t < NBLK) ? bsum[t] : 0;
    sd[t] = v;
    __syncthreads();
    #pragma unroll
    for (int off = 1; off < 256; off <<= 1) {
        int u = (t >= off) ? sd[t - off] : 0;
        __syncthreads();
        sd[t] += u;
        __syncthreads();
    }
    if (t < NBLK) boff[t] = sd[t] - v;          // exclusive
    if (t == NBLK - 1) rowstart[NN] = sd[t];    // total == EE
}

// pass 3: per-block exclusive scan + block offset -> rowstart
__global__ void scan_fin(const int* __restrict__ deg, const int* __restrict__ boff,
                         int* __restrict__ rowstart) {
    __shared__ int sd[256];
    const int t = (int)threadIdx.x;
    const int i = (int)blockIdx.x * 256 + t;
    const int v = (i < NN) ? deg[i] : 0;
    sd[t] = v;
    __syncthreads();
    #pragma unroll
    for (int off = 1; off < 256; off <<= 1) {
        int u = (t >= off) ? sd[t - off] : 0;
        __syncthreads();
        sd[t] += u;
        __syncthreads();
    }
    if (i < NN) rowstart[i] = boff[blockIdx.x] + sd[t] - v;
}

// atomic-free CSR fill using precomputed ranks
__global__ void fill_csr2(const int* __restrict__ src, const int* __restrict__ dst,
                          const int* __restrict__ rank, const int* __restrict__ rowstart,
                          int* __restrict__ col) {
    int e = blockIdx.x * blockDim.x + threadIdx.x;
    if (e < EE) col[rowstart[dst[e]] + rank[e]] = src[e];
}

// ---------------- input conversion / weight packing ----------------

// 8 elems/thread: write bf16 copy (GEMM operand) + fp8 copy (gather payload)
__global__ void cvt_x(const float* __restrict__ x, unsigned short* __restrict__ xb,
                      unsigned char* __restrict__ x8) {
    int i = blockIdx.x * blockDim.x + threadIdx.x;
    if (i >= PADN * 128 / 8) return;
    const int e0 = i * 8;
    float f[8];
    if (e0 + 8 <= NN * 128) {
        float4 u0 = *(const float4*)(x + e0);
        float4 u1 = *(const float4*)(x + e0 + 4);
        f[0] = u0.x; f[1] = u0.y; f[2] = u0.z; f[3] = u0.w;
        f[4] = u1.x; f[5] = u1.y; f[6] = u1.z; f[7] = u1.w;
    } else {
        #pragma unroll
        for (int k = 0; k < 8; ++k) f[k] = 0.f;   // pad rows (e0 >= NN*128 exactly)
    }
    uint4 b;
    b.x = (uint32)f2bf(f[0]) | ((uint32)f2bf(f[1]) << 16);
    b.y = (uint32)f2bf(f[2]) | ((uint32)f2bf(f[3]) << 16);
    b.z = (uint32)f2bf(f[4]) | ((uint32)f2bf(f[5]) << 16);
    b.w = (uint32)f2bf(f[6]) | ((uint32)f2bf(f[7]) << 16);
    *(uint4*)(xb + e0) = b;
    uint2 p;
    p.x = pkfp8(f[0], f[1], f[2], f[3]);
    p.y = pkfp8(f[4], f[5], f[6], f[7]);
    *(uint2*)(x8 + e0) = p;
}

// Wpack layout (bf16 elems): idx = ((s*16 + nf)*512 + l*8 + e)
//   s = mat*KS + ks (mat0=Wl, mat1=Wr), k = ks*32 + (l>>4)*8 + e, n = nf*16 + (l&15)
__global__ void pack_w(const float* __restrict__ Wl, const float* __restrict__ Wr,
                       unsigned short* __restrict__ Wpack, int C) {
    int idx = blockIdx.x * blockDim.x + threadIdx.x;
    if (idx >= 2 * C * 256) return;
    int e  = idx & 7;
    int l  = (idx >> 3) & 63;
    int nf = (idx >> 9) & 15;
    int s  = idx >> 13;
    int KS = C / 32;
    const float* W = (s < KS) ? Wl : Wr;
    int ks = (s < KS) ? s : s - KS;
    int k = ks * 32 + (l >> 4) * 8 + e;
    int n = nf * 16 + (l & 15);
    Wpack[idx] = f2bf(W[(size_t)k * HH + n]);
}

// ---------------- mean aggregation (fp8 gather -> bf16 out), one wave/node ----------------

__device__ __forceinline__ void acc8f(float* a, uint2 v) {
    f32x2 f0 = __builtin_amdgcn_cvt_pk_f32_fp8(v.x, false);
    f32x2 f1 = __builtin_amdgcn_cvt_pk_f32_fp8(v.x, true);
    f32x2 f2 = __builtin_amdgcn_cvt_pk_f32_fp8(v.y, false);
    f32x2 f3 = __builtin_amdgcn_cvt_pk_f32_fp8(v.y, true);
    a[0] += f0.x; a[1] += f0.y; a[2] += f1.x; a[3] += f1.y;
    a[4] += f2.x; a[5] += f2.y; a[6] += f3.x; a[7] += f3.y;
}

template<int C>
__global__ void agg_mean_8(const unsigned char* __restrict__ h8, const int* __restrict__ rowstart,
                           const int* __restrict__ col,
                           unsigned short* __restrict__ agg) {
    const int wid = (int)((blockIdx.x * blockDim.x + threadIdx.x) >> 6);
    const int l   = (int)(threadIdx.x & 63);
    if (wid >= NN) return;
    const int beg = rowstart[wid], end = rowstart[wid + 1];
    const int d   = end - beg;
    const float inv = 1.0f / (float)(d > 1 ? d : 1);
    float a[8] = {0.f, 0.f, 0.f, 0.f, 0.f, 0.f, 0.f, 0.f};

    if (C == 256) {
        const int half = l >> 5;            // 2 sub-waves x 32 lanes x 8B = 256B row
        const int cl   = l & 31;
        const unsigned char* base = h8 + cl * 8;
        int j = beg + half;
        for (; j + 6 < end; j += 8) {       // 4 independent gathers
            int c0 = col[j], c1 = col[j + 2], c2 = col[j + 4], c3 = col[j + 6];
            uint2 v0 = *(const uint2*)(base + (size_t)c0 * C);
            uint2 v1 = *(const uint2*)(base + (size_t)c1 * C);
            uint2 v2 = *(const uint2*)(base + (size_t)c2 * C);
            uint2 v3 = *(const uint2*)(base + (size_t)c3 * C);
            acc8f(a, v0); acc8f(a, v1); acc8f(a, v2); acc8f(a, v3);
        }
        for (; j < end; j += 2) {
            uint2 v0 = *(const uint2*)(base + (size_t)col[j] * C);
            acc8f(a, v0);
        }
        #pragma unroll
        for (int k = 0; k < 8; ++k) a[k] += __shfl_xor(a[k], 32, 64);
        if (half == 0) {
            uint4 o;
            o.x = (uint32)f2bf(a[0] * inv) | ((uint32)f2bf(a[1] * inv) << 16);
            o.y = (uint32)f2bf(a[2] * inv) | ((uint32)f2bf(a[3] * inv) << 16);
            o.z = (uint32)f2bf(a[4] * inv) | ((uint32)f2bf(a[5] * inv) << 16);
            o.w = (uint32)f2bf(a[6] * inv) | ((uint32)f2bf(a[7] * inv) << 16);
            *(uint4*)(agg + (size_t)wid * C + cl * 8) = o;
        }
    } else {  // C == 128
        const int q  = l >> 4;              // 4 sub-waves x 16 lanes x 8B = 128B row
        const int cl = l & 15;
        const unsigned char* base = h8 + cl * 8;
        int j = beg + q;
        for (; j + 12 < end; j += 16) {     // 4 independent gathers
            int c0 = col[j], c1 = col[j + 4], c2 = col[j + 8], c3 = col[j + 12];
            uint2 v0 = *(const uint2*)(base + (size_t)c0 * C);
            uint2 v1 = *(const uint2*)(base + (size_t)c1 * C);
            uint2 v2 = *(const uint2*)(base + (size_t)c2 * C);
            uint2 v3 = *(const uint2*)(base + (size_t)c3 * C);
            acc8f(a, v0); acc8f(a, v1); acc8f(a, v2); acc8f(a, v3);
        }
        for (; j < end; j += 4) {
            uint2 v0 = *(const uint2*)(base + (size_t)col[j] * C);
            acc8f(a, v0);
        }
        #pragma unroll
        for (int k = 0; k < 8; ++k) {
            a[k] += __shfl_xor(a[k], 16, 64);
            a[k] += __shfl_xor(a[k], 32, 64);
        }
        if (q == 0) {
            uint4 o;
            o.x = (uint32)f2bf(a[0] * inv) | ((uint32)f2bf(a[1] * inv) << 16);
            o.y = (uint32)f2bf(a[2] * inv) | ((uint32)f2bf(a[3] * inv) << 16);
            o.z = (uint32)f2bf(a[4] * inv) | ((uint32)f2bf(a[5] * inv) << 16);
            o.w = (uint32)f2bf(a[6] * inv) | ((uint32)f2bf(a[7] * inv) << 16);
            *(uint4*)(agg + (size_t)wid * C + cl * 8) = o;
        }
    }
}

// ---------------- MFMA GEMM: out = relu(BN(agg@Wl + h@Wr + b)) ----------------
// 64 rows x 256 cols per block, 4 waves (one per 64-col slab), K = 2*C fused.
// bf16 layers: C-tile repacked through LDS; writes bf16 h AND fp8 gather copy.

#define CPAD 260   // bf16 elems per Clds row (row stride 520 B; banks shift 2/row)

template<int C, bool FINAL>
__global__ __launch_bounds__(256)
void gemm_mfma(const unsigned short* __restrict__ Aagg, const unsigned short* __restrict__ Ain,
               const unsigned short* __restrict__ Wpack,
               const float* __restrict__ bias, const float* __restrict__ gamma,
               const float* __restrict__ beta, const float* __restrict__ rmean,
               const float* __restrict__ rvar,
               float* __restrict__ outf, unsigned short* __restrict__ outb,
               unsigned char* __restrict__ out8)
{
    constexpr int KS = C / 32;      // k-steps per matrix
    constexpr int S  = 2 * KS;      // fused K loop (agg@Wl then h@Wr)
    __shared__ unsigned short Alds[2][4][512];   // dbuf x 4 m-frags x (64 lanes * 8 bf16)
    __shared__ unsigned short Clds[64 * CPAD];   // bf16 C-tile repack (non-FINAL)
    const int tid = (int)threadIdx.x;
    const int wid = tid >> 6;       // wave -> 64-col slab
    const int l   = tid & 63;
    const int row0 = (int)blockIdx.x * 64;

    // staging address: wave wid stages m-frag wid
    const int srow  = row0 + wid * 16 + (l & 15);
    const int skoff = (l >> 4) * 8;

    f32x4 acc[4][4];
    #pragma unroll
    for (int m = 0; m < 4; ++m)
        #pragma unroll
        for (int n = 0; n < 4; ++n)
            acc[m][n] = (f32x4){0.f, 0.f, 0.f, 0.f};

    auto stage = [&](int buf, int s) {
        const unsigned short* Asrc = (s < KS) ? Aagg : Ain;
        const int ks = (s < KS) ? s : s - KS;
        const unsigned short* gp = Asrc + (size_t)srow * C + ks * 32 + skoff;
        __builtin_amdgcn_global_load_lds(
            (const __attribute__((address_space(1))) uint32*)gp,
            (__attribute__((address_space(3))) uint32*)(&Alds[buf][wid][0]),
            16, 0, 0);
    };

    stage(0, 0);
    int cur = 0;
    for (int s = 0; s < S; ++s) {
        __syncthreads();                       // Alds[cur] staged (vmcnt drained)
        if (s + 1 < S) stage(cur ^ 1, s + 1);  // prefetch next k-step
        short8 b[4];
        #pragma unroll
        for (int n = 0; n < 4; ++n) {
            size_t off = ((size_t)s * 16 + wid * 4 + n) * 512 + l * 8;
            b[n] = *(const short8*)(Wpack + off);
        }
        short8 a[4];
        #pragma unroll
        for (int m = 0; m < 4; ++m)
            a[m] = *(const short8*)(&Alds[cur][m][l * 8]);   // ds_read_b128, conflict-free
        #pragma unroll
        for (int m = 0; m < 4; ++m)
            #pragma unroll
            for (int n = 0; n < 4; ++n)
                acc[m][n] = __builtin_amdgcn_mfma_f32_16x16x32_bf16(a[m], b[n], acc[m][n], 0, 0, 0);
        cur ^= 1;
    }

    // epilogue: fold bias + BN + ReLU; C/D layout: col=lane&15, row=(lane>>4)*4+reg
    #pragma unroll
    for (int n = 0; n < 4; ++n) {
        const int jj = wid * 64 + n * 16 + (l & 15);
        const float sc = gamma[jj] * rsqrtf(rvar[jj] + EPSBN);
        const float c0 = (bias[jj] - rmean[jj]) * sc + beta[jj];
        #pragma unroll
        for (int m = 0; m < 4; ++m) {
            const int rb = m * 16 + (l >> 4) * 4;
            #pragma unroll
            for (int j = 0; j < 4; ++j) {
                float v = acc[m][n][j] * sc + c0;
                v = v > 0.f ? v : 0.f;
                if (FINAL) {
                    const int r = row0 + rb + j;
                    if (r < NN) outf[(size_t)r * HH + jj] = v;
                } else {
                    Clds[(rb + j) * CPAD + jj] = f2bf(v);
                }
            }
        }
    }
    if (!FINAL) {
        __syncthreads();
        // linear write-out: bf16 (16B/thread x8) + fp8 gather copy (8B/thread x8)
        #pragma unroll
        for (int i = 0; i < 8; ++i) {
            const int row  = i * 8 + (tid >> 5);
            const int col8 = (tid & 31) * 8;
            uint4 v = *(const uint4*)&Clds[row * CPAD + col8];
            *(uint4*)(outb + ((size_t)(row0 + row)) * HH + col8) = v;
            uint2 p;
            p.x = pkfp8(bf2f((unsigned short)(v.x & 0xffff)), bf2f((unsigned short)(v.x >> 16)),
                        bf2f((unsigned short)(v.y & 0xffff)), bf2f((unsigned short)(v.y >> 16)));
            p.y = pkfp8(bf2f((unsigned short)(v.z & 0xffff)), bf2f((unsigned short)(v.z >> 16)),
                        bf2f((unsigned short)(v.w & 0xffff)), bf2f((unsigned short)(v.w >> 16)));
            *(uint2*)(out8 + ((size_t)(row0 + row)) * HH + col8) = p;
        }
    }
}

// ---------------- launch ----------------

static inline size_t alignup(size_t x) { return (x + 511) & ~(size_t)511; }

extern "C" void kernel_launch(void* const* d_in, const int* in_sizes, int n_in,
                              void* d_out, int out_size, void* d_ws, size_t ws_size,
                              hipStream_t stream) {
    const float* x   = (const float*)d_in[0];
    const int*   ei  = (const int*)d_in[1];
    const int*   src = ei;
    const int*   dst = ei + EE;
    const float* gamma = (const float*)d_in[2];
    const float* beta  = (const float*)d_in[3];
    const float* rmean = (const float*)d_in[4];
    const float* rvar  = (const float*)d_in[5];
    const float* Wl0 = (const float*)d_in[6];
    const float* Wr0 = (const float*)d_in[7];
    const float* b0  = (const float*)d_in[8];
    const float* Wl1 = (const float*)d_in[9];
    const float* Wr1 = (const float*)d_in[10];
    const float* b1  = (const float*)d_in[11];
    const float* Wl2 = (const float*)d_in[12];
    const float* Wr2 = (const float*)d_in[13];
    const float* b2  = (const float*)d_in[14];
    float* out = (float*)d_out;
    (void)ws_size; (void)n_in; (void)in_sizes; (void)out_size;

    char* w = (char*)d_ws;
    size_t off = 0;
    int*   deg      = (int*)(w + off);   off += alignup(NN * 4);
    int*   rank     = (int*)(w + off);   off += alignup((size_t)EE * 4);
    int*   rowstart = (int*)(w + off);   off += alignup((NN + 1) * 4);
    int*   bsum     = (int*)(w + off);   off += alignup(NBLK * 4);
    int*   boff     = (int*)(w + off);   off += alignup(NBLK * 4);
    int*   col      = (int*)(w + off);   off += alignup((size_t)EE * 4);
    unsigned short* xb   = (unsigned short*)(w + off); off += alignup((size_t)PADN * 128 * 2);
    unsigned short* agg  = (unsigned short*)(w + off); off += alignup((size_t)PADN * HH * 2);
    unsigned short* h1   = (unsigned short*)(w + off); off += alignup((size_t)PADN * HH * 2);
    unsigned short* h2   = (unsigned short*)(w + off); off += alignup((size_t)PADN * HH * 2);
    unsigned char*  x8   = (unsigned char*)(w + off);  off += alignup((size_t)PADN * 128);
    unsigned char*  h1_8 = (unsigned char*)(w + off);  off += alignup((size_t)PADN * HH);
    unsigned char*  h2_8 = (unsigned char*)(w + off);  off += alignup((size_t)PADN * HH);
    unsigned short* Wp0  = (unsigned short*)(w + off); off += alignup((size_t)2 * 128 * 256 * 2);
    unsigned short* Wp1  = (unsigned short*)(w + off); off += alignup((size_t)2 * 256 * 256 * 2);
    unsigned short* Wp2  = (unsigned short*)(w + off); off += alignup((size_t)2 * 256 * 256 * 2);

    // CSR build (rank trick: fill pass is atomic-free)
    hipMemsetAsync(deg, 0, NN * 4, stream);
    count_rank<<<(EE + 255) / 256, 256, 0, stream>>>(dst, deg, rank);
    scan_part<<<NBLK, 256, 0, stream>>>(deg, bsum);
    scan_top <<<1, 256, 0, stream>>>(bsum, boff, rowstart);
    scan_fin <<<NBLK, 256, 0, stream>>>(deg, boff, rowstart);
    fill_csr2<<<(EE + 255) / 256, 256, 0, stream>>>(src, dst, rank, rowstart, col);

    // conversions / packing
    cvt_x <<<(PADN * 128 / 8 + 255) / 256, 256, 0, stream>>>(x, xb, x8);
    pack_w<<<(2 * 128 * 256 + 255) / 256, 256, 0, stream>>>(Wl0, Wr0, Wp0, 128);
    pack_w<<<(2 * 256 * 256 + 255) / 256, 256, 0, stream>>>(Wl1, Wr1, Wp1, 256);
    pack_w<<<(2 * 256 * 256 + 255) / 256, 256, 0, stream>>>(Wl2, Wr2, Wp2, 256);

    const int agg_grid  = (NN * 64 + 255) / 256;
    const int gemm_grid = PADN / 64;   // 782

    // layer 0 (C=128)
    agg_mean_8<128><<<agg_grid, 256, 0, stream>>>(x8, rowstart, col, agg);
    gemm_mfma<128, false><<<gemm_grid, 256, 0, stream>>>(agg, xb, Wp0,
        b0, gamma + 0 * HH, beta + 0 * HH, rmean + 0 * HH, rvar + 0 * HH, nullptr, h1, h1_8);

    // layer 1 (C=256)
    agg_mean_8<256><<<agg_grid, 256, 0, stream>>>(h1_8, rowstart, col, agg);
    gemm_mfma<256, false><<<gemm_grid, 256, 0, stream>>>(agg, h1, Wp1,
        b1, gamma + 1 * HH, beta + 1 * HH, rmean + 1 * HH, rvar + 1 * HH, nullptr, h2, h2_8);

    // layer 2 (C=256)
    agg_mean_8<256><<<agg_grid, 256, 0, stream>>>(h2_8, rowstart, col, agg);
    gemm_mfma<256, true><<<gemm_grid, 256, 0, stream>>>(agg, h2, Wp2,
        b2, gamma + 2 * HH, beta + 2 * HH, rmean + 2 * HH, rvar + 2 * HH, out, nullptr, nullptr);
}

// Round 7
// 340.313 us; speedup vs baseline: 3.1093x; 1.0303x over previous
//
#include <hip/hip_runtime.h>
#include <hip/hip_bf16.h>

#define NN 50000
#define PADN 50048            // 782*64 — padded row count for OOB-safe staging
#define EE 800000
#define HH 256
#define EPSBN 1e-5f
#define NBLK ((NN + 255) / 256)   // 196 scan blocks

typedef unsigned int uint32;
typedef __attribute__((ext_vector_type(8))) short short8;   // 8 bf16 = 4 VGPR
typedef __attribute__((ext_vector_type(4))) float f32x4;
typedef __attribute__((ext_vector_type(2))) float f32x2;

__device__ __forceinline__ float bf2f(unsigned short u) {
    union { uint32 u; float f; } c; c.u = ((uint32)u) << 16; return c.f;
}
__device__ __forceinline__ unsigned short f2bf(float f) {
    __hip_bfloat16 h = __float2bfloat16(f);   // RNE
    return *reinterpret_cast<unsigned short*>(&h);
}
// pack 4 floats -> 4 fp8 e4m3 (OCP on gfx950), RNE+sat
__device__ __forceinline__ uint32 pkfp8(float a, float b, float c, float d) {
    int r = 0;
    r = __builtin_amdgcn_cvt_pk_fp8_f32(a, b, r, false);   // bytes 0,1
    r = __builtin_amdgcn_cvt_pk_fp8_f32(c, d, r, true);    // bytes 2,3
    return (uint32)r;
}

// ---------------- CSR build ----------------

__global__ void count_rank(const int* __restrict__ dst, int* __restrict__ deg,
                           int* __restrict__ rank) {
    int e = blockIdx.x * blockDim.x + threadIdx.x;
    if (e < EE) rank[e] = atomicAdd(&deg[dst[e]], 1);
}

__global__ void scan_part(const int* __restrict__ deg, int* __restrict__ bsum) {
    __shared__ int sd[256];
    const int t = (int)threadIdx.x;
    const int i = (int)blockIdx.x * 256 + t;
    sd[t] = (i < NN) ? deg[i] : 0;
    __syncthreads();
    #pragma unroll
    for (int off = 128; off > 0; off >>= 1) {
        if (t < off) sd[t] += sd[t + off];
        __syncthreads();
    }
    if (t == 0) bsum[blockIdx.x] = sd[0];
}

__global__ void scan_top(const int* __restrict__ bsum, int* __restrict__ boff,
                         int* __restrict__ rowstart) {
    __shared__ int sd[256];
    const int t = (int)threadIdx.x;
    int v = (t < NBLK) ? bsum[t] : 0;
    sd[t] = v;
    __syncthreads();
    #pragma unroll
    for (int off = 1; off < 256; off <<= 1) {
        int u = (t >= off) ? sd[t - off] : 0;
        __syncthreads();
        sd[t] += u;
        __syncthreads();
    }
    if (t < NBLK) boff[t] = sd[t] - v;          // exclusive
    if (t == NBLK - 1) rowstart[NN] = sd[t];    // total == EE
}

__global__ void scan_fin(const int* __restrict__ deg, const int* __restrict__ boff,
                         int* __restrict__ rowstart) {
    __shared__ int sd[256];
    const int t = (int)threadIdx.x;
    const int i = (int)blockIdx.x * 256 + t;
    const int v = (i < NN) ? deg[i] : 0;
    sd[t] = v;
    __syncthreads();
    #pragma unroll
    for (int off = 1; off < 256; off <<= 1) {
        int u = (t >= off) ? sd[t - off] : 0;
        __syncthreads();
        sd[t] += u;
        __syncthreads();
    }
    if (i < NN) rowstart[i] = boff[blockIdx.x] + sd[t] - v;
}

__global__ void fill_csr2(const int* __restrict__ src, const int* __restrict__ dst,
                          const int* __restrict__ rank, const int* __restrict__ rowstart,
                          int* __restrict__ col) {
    int e = blockIdx.x * blockDim.x + threadIdx.x;
    if (e < EE) col[rowstart[dst[e]] + rank[e]] = src[e];
}

// ---------------- input conversion / weight packing ----------------

__global__ void cvt_x(const float* __restrict__ x, unsigned short* __restrict__ xb,
                      unsigned char* __restrict__ x8) {
    int i = blockIdx.x * blockDim.x + threadIdx.x;
    if (i >= PADN * 128 / 8) return;
    const int e0 = i * 8;
    float f[8];
    if (e0 + 8 <= NN * 128) {
        float4 u0 = *(const float4*)(x + e0);
        float4 u1 = *(const float4*)(x + e0 + 4);
        f[0] = u0.x; f[1] = u0.y; f[2] = u0.z; f[3] = u0.w;
        f[4] = u1.x; f[5] = u1.y; f[6] = u1.z; f[7] = u1.w;
    } else {
        #pragma unroll
        for (int k = 0; k < 8; ++k) f[k] = 0.f;   // pad rows
    }
    uint4 b;
    b.x = (uint32)f2bf(f[0]) | ((uint32)f2bf(f[1]) << 16);
    b.y = (uint32)f2bf(f[2]) | ((uint32)f2bf(f[3]) << 16);
    b.z = (uint32)f2bf(f[4]) | ((uint32)f2bf(f[5]) << 16);
    b.w = (uint32)f2bf(f[6]) | ((uint32)f2bf(f[7]) << 16);
    *(uint4*)(xb + e0) = b;
    uint2 p;
    p.x = pkfp8(f[0], f[1], f[2], f[3]);
    p.y = pkfp8(f[4], f[5], f[6], f[7]);
    *(uint2*)(x8 + e0) = p;
}

// Wpack layout (bf16 elems): idx = ((s*16 + nf)*512 + l*8 + e)
__global__ void pack_w(const float* __restrict__ Wl, const float* __restrict__ Wr,
                       unsigned short* __restrict__ Wpack, int C) {
    int idx = blockIdx.x * blockDim.x + threadIdx.x;
    if (idx >= 2 * C * 256) return;
    int e  = idx & 7;
    int l  = (idx >> 3) & 63;
    int nf = (idx >> 9) & 15;
    int s  = idx >> 13;
    int KS = C / 32;
    const float* W = (s < KS) ? Wl : Wr;
    int ks = (s < KS) ? s : s - KS;
    int k = ks * 32 + (l >> 4) * 8 + e;
    int n = nf * 16 + (l & 15);
    Wpack[idx] = f2bf(W[(size_t)k * HH + n]);
}

// ---------------- mean aggregation (fp8 gather -> bf16 out), one wave/node ----------------

__device__ __forceinline__ void acc8f(float* a, uint2 v) {
    f32x2 f0 = __builtin_amdgcn_cvt_pk_f32_fp8(v.x, false);
    f32x2 f1 = __builtin_amdgcn_cvt_pk_f32_fp8(v.x, true);
    f32x2 f2 = __builtin_amdgcn_cvt_pk_f32_fp8(v.y, false);
    f32x2 f3 = __builtin_amdgcn_cvt_pk_f32_fp8(v.y, true);
    a[0] += f0.x; a[1] += f0.y; a[2] += f1.x; a[3] += f1.y;
    a[4] += f2.x; a[5] += f2.y; a[6] += f3.x; a[7] += f3.y;
}

template<int C>
__global__ void agg_mean_8(const unsigned char* __restrict__ h8, const int* __restrict__ rowstart,
                           const int* __restrict__ col,
                           unsigned short* __restrict__ agg) {
    const int wid = (int)((blockIdx.x * blockDim.x + threadIdx.x) >> 6);
    const int l   = (int)(threadIdx.x & 63);
    if (wid >= NN) return;
    const int beg = rowstart[wid], end = rowstart[wid + 1];
    const int d   = end - beg;
    const float inv = 1.0f / (float)(d > 1 ? d : 1);
    float a[8] = {0.f, 0.f, 0.f, 0.f, 0.f, 0.f, 0.f, 0.f};

    if (C == 256) {
        const int half = l >> 5;
        const int cl   = l & 31;
        const unsigned char* base = h8 + cl * 8;
        int j = beg + half;
        for (; j + 6 < end; j += 8) {
            int c0 = col[j], c1 = col[j + 2], c2 = col[j + 4], c3 = col[j + 6];
            uint2 v0 = *(const uint2*)(base + (size_t)c0 * C);
            uint2 v1 = *(const uint2*)(base + (size_t)c1 * C);
            uint2 v2 = *(const uint2*)(base + (size_t)c2 * C);
            uint2 v3 = *(const uint2*)(base + (size_t)c3 * C);
            acc8f(a, v0); acc8f(a, v1); acc8f(a, v2); acc8f(a, v3);
        }
        for (; j < end; j += 2) {
            uint2 v0 = *(const uint2*)(base + (size_t)col[j] * C);
            acc8f(a, v0);
        }
        #pragma unroll
        for (int k = 0; k < 8; ++k) a[k] += __shfl_xor(a[k], 32, 64);
        if (half == 0) {
            uint4 o;
            o.x = (uint32)f2bf(a[0] * inv) | ((uint32)f2bf(a[1] * inv) << 16);
            o.y = (uint32)f2bf(a[2] * inv) | ((uint32)f2bf(a[3] * inv) << 16);
            o.z = (uint32)f2bf(a[4] * inv) | ((uint32)f2bf(a[5] * inv) << 16);
            o.w = (uint32)f2bf(a[6] * inv) | ((uint32)f2bf(a[7] * inv) << 16);
            *(uint4*)(agg + (size_t)wid * C + cl * 8) = o;
        }
    } else {  // C == 128
        const int q  = l >> 4;
        const int cl = l & 15;
        const unsigned char* base = h8 + cl * 8;
        int j = beg + q;
        for (; j + 12 < end; j += 16) {
            int c0 = col[j], c1 = col[j + 4], c2 = col[j + 8], c3 = col[j + 12];
            uint2 v0 = *(const uint2*)(base + (size_t)c0 * C);
            uint2 v1 = *(const uint2*)(base + (size_t)c1 * C);
            uint2 v2 = *(const uint2*)(base + (size_t)c2 * C);
            uint2 v3 = *(const uint2*)(base + (size_t)c3 * C);
            acc8f(a, v0); acc8f(a, v1); acc8f(a, v2); acc8f(a, v3);
        }
        for (; j < end; j += 4) {
            uint2 v0 = *(const uint2*)(base + (size_t)col[j] * C);
            acc8f(a, v0);
        }
        #pragma unroll
        for (int k = 0; k < 8; ++k) {
            a[k] += __shfl_xor(a[k], 16, 64);
            a[k] += __shfl_xor(a[k], 32, 64);
        }
        if (q == 0) {
            uint4 o;
            o.x = (uint32)f2bf(a[0] * inv) | ((uint32)f2bf(a[1] * inv) << 16);
            o.y = (uint32)f2bf(a[2] * inv) | ((uint32)f2bf(a[3] * inv) << 16);
            o.z = (uint32)f2bf(a[4] * inv) | ((uint32)f2bf(a[5] * inv) << 16);
            o.w = (uint32)f2bf(a[6] * inv) | ((uint32)f2bf(a[7] * inv) << 16);
            *(uint4*)(agg + (size_t)wid * C + cl * 8) = o;
        }
    }
}

// ---------------- MFMA GEMM: out = relu(BN(agg@Wl + h@Wr + b)) ----------------
// 64 rows x 256 cols per block, 4 waves (one per 64-col slab), K = 2*C fused.
// BK=64: two k-steps per barrier pair (32 MFMA/stage). Output staged through
// LDS for fully-coalesced stores (f32 in two 32-row half-passes for FINAL).

#define CPAD 260   // padded cols (f32 rows: stride 1040B; bf16 rows: 520B)

template<int C, bool FINAL>
__global__ __launch_bounds__(256)
void gemm_mfma(const unsigned short* __restrict__ Aagg, const unsigned short* __restrict__ Ain,
               const unsigned short* __restrict__ Wpack,
               const float* __restrict__ bias, const float* __restrict__ gamma,
               const float* __restrict__ beta, const float* __restrict__ rmean,
               const float* __restrict__ rvar,
               float* __restrict__ outf, unsigned short* __restrict__ outb,
               unsigned char* __restrict__ out8)
{
    constexpr int KS = C / 32;      // k-steps per matrix
    constexpr int S  = 2 * KS;      // total k-steps (agg@Wl then h@Wr)
    constexpr int NS = S / 2;       // stages (2 k-steps each)
    __shared__ unsigned short Alds[2][4][1024];      // dbuf x m-frag x (2 ksteps * 512)
    __shared__ __align__(16) unsigned char Cbuf[33280];  // f32 32xCPAD | bf16 64xCPAD
    const int tid = (int)threadIdx.x;
    const int wid = tid >> 6;       // wave -> 64-col slab
    const int l   = tid & 63;
    const int row0 = (int)blockIdx.x * 64;

    const int srow  = row0 + wid * 16 + (l & 15);
    const int skoff = (l >> 4) * 8;

    f32x4 acc[4][4];
    #pragma unroll
    for (int m = 0; m < 4; ++m)
        #pragma unroll
        for (int n = 0; n < 4; ++n)
            acc[m][n] = (f32x4){0.f, 0.f, 0.f, 0.f};

    auto stage = [&](int buf, int st) {
        #pragma unroll
        for (int k2 = 0; k2 < 2; ++k2) {
            const int s = st * 2 + k2;
            const unsigned short* Asrc = (s < KS) ? Aagg : Ain;
            const int ks = (s < KS) ? s : s - KS;
            const unsigned short* gp = Asrc + (size_t)srow * C + ks * 32 + skoff;
            __builtin_amdgcn_global_load_lds(
                (const __attribute__((address_space(1))) uint32*)gp,
                (__attribute__((address_space(3))) uint32*)(&Alds[buf][wid][k2 * 512]),
                16, 0, 0);
        }
    };

    stage(0, 0);
    int cur = 0;
    for (int st = 0; st < NS; ++st) {
        __syncthreads();                        // Alds[cur] staged (vmcnt drained)
        if (st + 1 < NS) stage(cur ^ 1, st + 1);
        short8 b[2][4];
        #pragma unroll
        for (int k2 = 0; k2 < 2; ++k2)
            #pragma unroll
            for (int n = 0; n < 4; ++n) {
                size_t off = ((size_t)(st * 2 + k2) * 16 + wid * 4 + n) * 512 + l * 8;
                b[k2][n] = *(const short8*)(Wpack + off);
            }
        short8 a[2][4];
        #pragma unroll
        for (int k2 = 0; k2 < 2; ++k2)
            #pragma unroll
            for (int m = 0; m < 4; ++m)
                a[k2][m] = *(const short8*)(&Alds[cur][m][k2 * 512 + l * 8]);
        #pragma unroll
        for (int k2 = 0; k2 < 2; ++k2)
            #pragma unroll
            for (int m = 0; m < 4; ++m)
                #pragma unroll
                for (int n = 0; n < 4; ++n)
                    acc[m][n] = __builtin_amdgcn_mfma_f32_16x16x32_bf16(a[k2][m], b[k2][n], acc[m][n], 0, 0, 0);
        cur ^= 1;
    }

    // BN constants per output column (4 n-frags)
    float sj[4], cj[4];
    #pragma unroll
    for (int n = 0; n < 4; ++n) {
        const int jj = wid * 64 + n * 16 + (l & 15);
        sj[n] = gamma[jj] * rsqrtf(rvar[jj] + EPSBN);
        cj[n] = (bias[jj] - rmean[jj]) * sj[n] + beta[jj];
    }

    if (FINAL) {
        // two half-passes: rows 0-31 (m=0,1) then 32-63 (m=2,3), f32 through LDS
        float* Cf = (float*)Cbuf;
        #pragma unroll
        for (int half = 0; half < 2; ++half) {
            if (half) __syncthreads();          // protect Cf reuse
            #pragma unroll
            for (int n = 0; n < 4; ++n) {
                const int jj = wid * 64 + n * 16 + (l & 15);
                #pragma unroll
                for (int mm = 0; mm < 2; ++mm) {
                    const int m  = half * 2 + mm;
                    const int rb = mm * 16 + (l >> 4) * 4;   // 0..31 within half
                    #pragma unroll
                    for (int j = 0; j < 4; ++j) {
                        float v = acc[m][n][j] * sj[n] + cj[n];
                        Cf[(rb + j) * CPAD + jj] = v > 0.f ? v : 0.f;
                    }
                }
            }
            __syncthreads();
            const int col4 = (tid & 63) * 4;
            const int rw   = tid >> 6;
            #pragma unroll
            for (int i = 0; i < 8; ++i) {
                const int row  = i * 4 + rw;
                const int grow = row0 + half * 32 + row;
                if (grow < NN) {
                    float4 v = *(const float4*)&Cf[row * CPAD + col4];
                    *(float4*)(outf + (size_t)grow * HH + col4) = v;
                }
            }
        }
    } else {
        unsigned short* Clds = (unsigned short*)Cbuf;
        #pragma unroll
        for (int n = 0; n < 4; ++n) {
            const int jj = wid * 64 + n * 16 + (l & 15);
            #pragma unroll
            for (int m = 0; m < 4; ++m) {
                const int rb = m * 16 + (l >> 4) * 4;
                #pragma unroll
                for (int j = 0; j < 4; ++j) {
                    float v = acc[m][n][j] * sj[n] + cj[n];
                    Clds[(rb + j) * CPAD + jj] = f2bf(v > 0.f ? v : 0.f);
                }
            }
        }
        __syncthreads();
        // linear write-out: bf16 (16B/thread x8) + fp8 gather copy (8B/thread x8)
        #pragma unroll
        for (int i = 0; i < 8; ++i) {
            const int row  = i * 8 + (tid >> 5);
            const int col8 = (tid & 31) * 8;
            uint4 v = *(const uint4*)&Clds[row * CPAD + col8];
            *(uint4*)(outb + ((size_t)(row0 + row)) * HH + col8) = v;
            uint2 p;
            p.x = pkfp8(bf2f((unsigned short)(v.x & 0xffff)), bf2f((unsigned short)(v.x >> 16)),
                        bf2f((unsigned short)(v.y & 0xffff)), bf2f((unsigned short)(v.y >> 16)));
            p.y = pkfp8(bf2f((unsigned short)(v.z & 0xffff)), bf2f((unsigned short)(v.z >> 16)),
                        bf2f((unsigned short)(v.w & 0xffff)), bf2f((unsigned short)(v.w >> 16)));
            *(uint2*)(out8 + ((size_t)(row0 + row)) * HH + col8) = p;
        }
    }
}

// ---------------- launch ----------------

static inline size_t alignup(size_t x) { return (x + 511) & ~(size_t)511; }

extern "C" void kernel_launch(void* const* d_in, const int* in_sizes, int n_in,
                              void* d_out, int out_size, void* d_ws, size_t ws_size,
                              hipStream_t stream) {
    const float* x   = (const float*)d_in[0];
    const int*   ei  = (const int*)d_in[1];
    const int*   src = ei;
    const int*   dst = ei + EE;
    const float* gamma = (const float*)d_in[2];
    const float* beta  = (const float*)d_in[3];
    const float* rmean = (const float*)d_in[4];
    const float* rvar  = (const float*)d_in[5];
    const float* Wl0 = (const float*)d_in[6];
    const float* Wr0 = (const float*)d_in[7];
    const float* b0  = (const float*)d_in[8];
    const float* Wl1 = (const float*)d_in[9];
    const float* Wr1 = (const float*)d_in[10];
    const float* b1  = (const float*)d_in[11];
    const float* Wl2 = (const float*)d_in[12];
    const float* Wr2 = (const float*)d_in[13];
    const float* b2  = (const float*)d_in[14];
    float* out = (float*)d_out;
    (void)ws_size; (void)n_in; (void)in_sizes; (void)out_size;

    char* w = (char*)d_ws;
    size_t off = 0;
    int*   deg      = (int*)(w + off);   off += alignup(NN * 4);
    int*   rank     = (int*)(w + off);   off += alignup((size_t)EE * 4);
    int*   rowstart = (int*)(w + off);   off += alignup((NN + 1) * 4);
    int*   bsum     = (int*)(w + off);   off += alignup(NBLK * 4);
    int*   boff     = (int*)(w + off);   off += alignup(NBLK * 4);
    int*   col      = (int*)(w + off);   off += alignup((size_t)EE * 4);
    unsigned short* xb   = (unsigned short*)(w + off); off += alignup((size_t)PADN * 128 * 2);
    unsigned short* agg  = (unsigned short*)(w + off); off += alignup((size_t)PADN * HH * 2);
    unsigned short* h1   = (unsigned short*)(w + off); off += alignup((size_t)PADN * HH * 2);
    unsigned short* h2   = (unsigned short*)(w + off); off += alignup((size_t)PADN * HH * 2);
    unsigned char*  x8   = (unsigned char*)(w + off);  off += alignup((size_t)PADN * 128);
    unsigned char*  h1_8 = (unsigned char*)(w + off);  off += alignup((size_t)PADN * HH);
    unsigned char*  h2_8 = (unsigned char*)(w + off);  off += alignup((size_t)PADN * HH);
    unsigned short* Wp0  = (unsigned short*)(w + off); off += alignup((size_t)2 * 128 * 256 * 2);
    unsigned short* Wp1  = (unsigned short*)(w + off); off += alignup((size_t)2 * 256 * 256 * 2);
    unsigned short* Wp2  = (unsigned short*)(w + off); off += alignup((size_t)2 * 256 * 256 * 2);

    // CSR build (rank trick: fill pass is atomic-free)
    hipMemsetAsync(deg, 0, NN * 4, stream);
    count_rank<<<(EE + 255) / 256, 256, 0, stream>>>(dst, deg, rank);
    scan_part<<<NBLK, 256, 0, stream>>>(deg, bsum);
    scan_top <<<1, 256, 0, stream>>>(bsum, boff, rowstart);
    scan_fin <<<NBLK, 256, 0, stream>>>(deg, boff, rowstart);
    fill_csr2<<<(EE + 255) / 256, 256, 0, stream>>>(src, dst, rank, rowstart, col);

    // conversions / packing
    cvt_x <<<(PADN * 128 / 8 + 255) / 256, 256, 0, stream>>>(x, xb, x8);
    pack_w<<<(2 * 128 * 256 + 255) / 256, 256, 0, stream>>>(Wl0, Wr0, Wp0, 128);
    pack_w<<<(2 * 256 * 256 + 255) / 256, 256, 0, stream>>>(Wl1, Wr1, Wp1, 256);
    pack_w<<<(2 * 256 * 256 + 255) / 256, 256, 0, stream>>>(Wl2, Wr2, Wp2, 256);

    const int agg_grid  = (NN * 64 + 255) / 256;
    const int gemm_grid = PADN / 64;   // 782

    // layer 0 (C=128)
    agg_mean_8<128><<<agg_grid, 256, 0, stream>>>(x8, rowstart, col, agg);
    gemm_mfma<128, false><<<gemm_grid, 256, 0, stream>>>(agg, xb, Wp0,
        b0, gamma + 0 * HH, beta + 0 * HH, rmean + 0 * HH, rvar + 0 * HH, nullptr, h1, h1_8);

    // layer 1 (C=256)
    agg_mean_8<256><<<agg_grid, 256, 0, stream>>>(h1_8, rowstart, col, agg);
    gemm_mfma<256, false><<<gemm_grid, 256, 0, stream>>>(agg, h1, Wp1,
        b1, gamma + 1 * HH, beta + 1 * HH, rmean + 1 * HH, rvar + 1 * HH, nullptr, h2, h2_8);

    // layer 2 (C=256)
    agg_mean_8<256><<<agg_grid, 256, 0, stream>>>(h2_8, rowstart, col, agg);
    gemm_mfma<256, true><<<gemm_grid, 256, 0, stream>>>(agg, h2, Wp2,
        b2, gamma + 2 * HH, beta + 2 * HH, rmean + 2 * HH, rvar + 2 * HH, out, nullptr, nullptr);
}